// Round 14
// baseline (213.415 us; speedup 1.0000x reference)
//
#include <hip/hip_runtime.h>

typedef float f32x4 __attribute__((ext_vector_type(4)));
typedef __bf16 bf16x8 __attribute__((ext_vector_type(8)));

static __device__ __forceinline__ unsigned short f2bf(float f) {
    unsigned int u = __builtin_bit_cast(unsigned int, f);
    u += 0x7fffu + ((u >> 16) & 1u);
    return (unsigned short)(u >> 16);
}
static __device__ __forceinline__ unsigned short bfc(float f) {
    return __builtin_bit_cast(unsigned short, (__bf16)f);
}

#define QSC 0.18033688011112042f   // log2(e)/sqrt(HD) folded into Q

typedef const __attribute__((address_space(1))) unsigned int gu32;
typedef __attribute__((address_space(3))) unsigned int lu32;
static __device__ __forceinline__ void gload_lds16(const unsigned short* g, unsigned short* l) {
    __builtin_amdgcn_global_load_lds((gu32*)g, (lu32*)l, 16, 0, 0);
}

// ---------------- fp32 -> bf16 elementwise convert ----------------
__global__ __launch_bounds__(256)
void cvt_bf16(const float* __restrict__ in, unsigned short* __restrict__ out) {
    int i = blockIdx.x * 256 + threadIdx.x;
    const float4* p = (const float4*)in + (size_t)i * 2;
    float4 a = p[0], b = p[1];
    union { unsigned short s[8]; uint4 v; } u;
    u.s[0] = f2bf(a.x); u.s[1] = f2bf(a.y); u.s[2] = f2bf(a.z); u.s[3] = f2bf(a.w);
    u.s[4] = f2bf(b.x); u.s[5] = f2bf(b.y); u.s[6] = f2bf(b.z); u.s[7] = f2bf(b.w);
    ((uint4*)out)[i] = u.v;
}

// ---------------- weight transpose+convert: w[K][N] fp32 -> wT[N][K] bf16 ----------------
__global__ __launch_bounds__(256)
void transpose_w(const float* __restrict__ w, unsigned short* __restrict__ wT,
                 int K, int N) {
    __shared__ unsigned short Lt[64][65];
    const int k0 = blockIdx.x * 64, n0 = blockIdx.y * 64;
    const int t = threadIdx.x;
    const int r = t >> 4, c4 = (t & 15) * 4;
    #pragma unroll
    for (int i = 0; i < 4; i++) {
        int rr = r + i * 16;
        float4 v = *(const float4*)(w + (k0 + rr) * N + n0 + c4);
        Lt[rr][c4 + 0] = f2bf(v.x); Lt[rr][c4 + 1] = f2bf(v.y);
        Lt[rr][c4 + 2] = f2bf(v.z); Lt[rr][c4 + 3] = f2bf(v.w);
    }
    __syncthreads();
    const int rn = t >> 3, ks = (t & 7) * 8;
    #pragma unroll
    for (int i = 0; i < 2; i++) {
        int rr = rn + i * 32;
        unsigned short tmp[8];
        #pragma unroll
        for (int j = 0; j < 8; j++) tmp[j] = Lt[ks + j][rr];
        *(uint4*)(wT + (n0 + rr) * K + k0 + ks) = *(const uint4*)tmp;
    }
}

// ---------------- QKV GEMM (2-phase prefetch + granule swizzle, r10-proven) ----------------
__global__ __launch_bounds__(256)
void qkv_gemm2(const unsigned short* __restrict__ A,
               const unsigned short* __restrict__ Bt,
               const float* __restrict__ bias,
               unsigned short* __restrict__ q_ws,
               unsigned short* __restrict__ k_ws,
               unsigned short* __restrict__ vT_ws)
{
    const int K = 1024;
    __shared__ unsigned short Al[2][128 * 32];
    __shared__ unsigned short Bl[2][128 * 32];
    const int tid = threadIdx.x;
    const int lane = tid & 63, w = tid >> 6;
    const int l15 = lane & 15, lhi = lane >> 4;
    const int m0 = blockIdx.x * 128, n0 = blockIdx.y * 128;
    const int wm = (w >> 1) * 64, wn = (w & 1) * 64;

    const int srow = w * 32 + (lane >> 2);
    const int sg = ((lane & 3) ^ ((lane >> 3) & 3)) * 8;
    const unsigned short* ga = A + (size_t)(m0 + srow) * K + sg;
    const unsigned short* gb = Bt + (size_t)(n0 + srow) * K + sg;
    const int lofs = w * 32 * 32;

    const int rc = (lhi ^ ((l15 >> 1) & 3)) * 8;

    f32x4 acc[4][4] = {};

    gload_lds16(ga, &Al[0][lofs]);
    gload_lds16(ga + 16 * K, &Al[0][lofs + 512]);
    gload_lds16(gb, &Bl[0][lofs]);
    gload_lds16(gb + 16 * K, &Bl[0][lofs + 512]);
    __syncthreads();

    int cur = 0;
    for (int k0 = 0; k0 < K; k0 += 32) {
        const int nxt = cur ^ 1;
        if (k0 + 32 < K) {
            gload_lds16(ga + k0 + 32,          &Al[nxt][lofs]);
            gload_lds16(ga + k0 + 32 + 16 * K, &Al[nxt][lofs + 512]);
            gload_lds16(gb + k0 + 32,          &Bl[nxt][lofs]);
            gload_lds16(gb + k0 + 32 + 16 * K, &Bl[nxt][lofs + 512]);
        }
        bf16x8 af[4], bfr[4];
        #pragma unroll
        for (int m = 0; m < 4; m++)
            af[m] = *(const bf16x8*)(&Al[cur][(wm + m * 16 + l15) * 32 + rc]);
        #pragma unroll
        for (int n = 0; n < 4; n++)
            bfr[n] = *(const bf16x8*)(&Bl[cur][(wn + n * 16 + l15) * 32 + rc]);
        __builtin_amdgcn_s_setprio(1);
        #pragma unroll
        for (int m = 0; m < 4; m++)
            #pragma unroll
            for (int n = 0; n < 4; n++)
                acc[m][n] = __builtin_amdgcn_mfma_f32_16x16x32_bf16(af[m], bfr[n], acc[m][n], 0, 0, 0);
        __builtin_amdgcn_s_setprio(0);
        __syncthreads();
        cur = nxt;
    }

    #pragma unroll
    for (int n = 0; n < 4; n++) {
        int col = n0 + wn + n * 16 + l15;
        float bv = bias[col];
        int which = col >> 10;          // 0=Q 1=K 2=V (wave/block-uniform per n)
        int d = col & 1023;
        int h = d >> 6, hd = d & 63;
        if (which == 2) {
            // V: pack 4 consecutive t per lane -> ushort4 store (write-combines to ~1x)
            #pragma unroll
            for (int m = 0; m < 4; m++) {
                int row0 = m0 + wm + m * 16 + lhi * 4;
                int b = row0 >> 11, t0 = row0 & 2047;
                ushort4 pk;
                pk.x = f2bf(acc[m][n][0] + bv);
                pk.y = f2bf(acc[m][n][1] + bv);
                pk.z = f2bf(acc[m][n][2] + bv);
                pk.w = f2bf(acc[m][n][3] + bv);
                *(ushort4*)(&vT_ws[((size_t)(b * 16 + h) * 64 + hd) * 2048 + t0]) = pk;
            }
        } else {
            #pragma unroll
            for (int m = 0; m < 4; m++) {
                #pragma unroll
                for (int j = 0; j < 4; j++) {
                    int row = m0 + wm + m * 16 + lhi * 4 + j;
                    int b = row >> 11, t = row & 2047;
                    float val = acc[m][n][j] + bv;
                    int bh = b * 16 + h;
                    if (which == 0) q_ws[(bh * 2048 + t) * 64 + hd] = f2bf(val * QSC);
                    else            k_ws[(bh * 2048 + t) * 64 + hd] = f2bf(val);
                }
            }
        }
    }
}

// ---------------- Flash attention (causal) ----------------
// m=2: each wave owns 32 q-rows -> K/V LDS fragment reads amortized over 2x rows
// (LDS pipe was ~60% of attn time). QB=256, one q-block per block; slot->qb map
// {0,1,2,3,7,6,5,4} balances CU pairs under round-robin dispatch (slots p,p+4).
// No-max softmax (r13-proven), osum via MFMA ones-column.
#define LKK 72

__global__ __launch_bounds__(512, 4)
void attn_fwd(const unsigned short* __restrict__ q_ws,
              const unsigned short* __restrict__ k_ws,
              const unsigned short* __restrict__ vT_ws,
              unsigned short* __restrict__ attn_ws)
{
    __shared__ unsigned short Kb[2][64 * LKK];      // 18 KB
    __shared__ unsigned short Vb[2][64 * LKK];      // 18 KB
    __shared__ unsigned short Pl[8][2][16 * 64];    // 32 KB  (total 68 KB)

    const int bh = blockIdx.x;
    const int slot = blockIdx.y;
    const int qb = (slot < 4) ? slot : (11 - slot);   // {0,1,2,3,7,6,5,4}
    const int b = bh >> 4, h = bh & 15;
    const int tid = threadIdx.x;
    const int lane = tid & 63, wid = tid >> 6;
    const int l15 = lane & 15, lhi = lane >> 4;
    const int tbase = bh * 2048;
    const float NINF = -__builtin_inff();

    const int r0 = tid >> 3;
    const int c0 = (tid & 7) * 8;
    const unsigned short* kg = k_ws + (size_t)(tbase + r0) * 64 + c0;
    const unsigned short* vg = vT_ws + ((size_t)bh * 64 + r0) * 2048 + c0;

    const int xr = l15 & 7;

    bf16x8 ones;
    #pragma unroll
    for (int z = 0; z < 8; z++) ones[z] = (__bf16)1.0f;

    const int qrow = qb * 256 + wid * 32;      // wave owns rows qrow..qrow+31
    const int nkv = 4 * (qb + 1);

    bf16x8 qf[2][2];
    #pragma unroll
    for (int m = 0; m < 2; m++)
        #pragma unroll
        for (int ks = 0; ks < 2; ks++)
            qf[m][ks] = *(const bf16x8*)(q_ws + (size_t)(tbase + qrow + m * 16 + l15) * 64 + ks * 32 + lhi * 8);

    f32x4 o[2][4] = {};
    f32x4 osum[2] = {};

    {
        uint4 ka = *(const uint4*)(kg);
        uint4 va = *(const uint4*)(vg);
        *(uint4*)(&Kb[0][r0 * LKK + c0]) = ka;
        *(uint4*)(&Vb[0][r0 * LKK + c0]) = va;
    }
    __syncthreads();

    int cur = 0;
    for (int kb = 0; kb < nkv; ++kb) {
        const int k0 = kb * 64;
        const int knx = (kb + 1 < nkv ? kb + 1 : kb) * 64;
        uint4 ka = *(const uint4*)(kg + (size_t)knx * 64);
        uint4 va = *(const uint4*)(vg + knx);

        if (k0 <= qrow + 31) {
            // S^T = K Q^T : q = l15 (per m-half), k = 16n + 4*lhi + j
            f32x4 s[2][4] = {};
            __builtin_amdgcn_s_setprio(1);
            #pragma unroll
            for (int ks = 0; ks < 2; ks++) {
                bf16x8 kf[4];
                #pragma unroll
                for (int n = 0; n < 4; n++)
                    kf[n] = *(const bf16x8*)(&Kb[cur][(n * 16 + l15) * LKK + ks * 32 + lhi * 8]);
                #pragma unroll
                for (int m = 0; m < 2; m++)
                    #pragma unroll
                    for (int n = 0; n < 4; n++)
                        s[m][n] = __builtin_amdgcn_mfma_f32_16x16x32_bf16(kf[n], qf[m][ks], s[m][n], 0, 0, 0);
            }
            __builtin_amdgcn_s_setprio(0);
            // causal mask: only tiles crossing the diagonal
            if (k0 + 63 > qrow) {
                #pragma unroll
                for (int m = 0; m < 2; m++) {
                    int qg = qrow + m * 16 + l15;
                    #pragma unroll
                    for (int n = 0; n < 4; n++) {
                        int kgl = k0 + n * 16 + lhi * 4;
                        #pragma unroll
                        for (int j = 0; j < 4; j++)
                            s[m][n][j] = (kgl + j <= qg) ? s[m][n][j] : NINF;
                    }
                }
            }
            // un-subtracted softmax: p = 2^s (masked -> 0)
            #pragma unroll
            for (int m = 0; m < 2; m++)
                #pragma unroll
                for (int n = 0; n < 4; n++)
                    #pragma unroll
                    for (int j = 0; j < 4; j++)
                        s[m][n][j] = exp2f(s[m][n][j]);
            // P -> LDS, swizzled 8B writes
            #pragma unroll
            for (int m = 0; m < 2; m++)
                #pragma unroll
                for (int n = 0; n < 4; n++) {
                    ushort4 pk;
                    pk.x = bfc(s[m][n][0]); pk.y = bfc(s[m][n][1]);
                    pk.z = bfc(s[m][n][2]); pk.w = bfc(s[m][n][3]);
                    int chunk = (2 * n + (lhi >> 1)) ^ xr;
                    *(ushort4*)(&Pl[wid][m][l15 * 64 + chunk * 8 + (lhi & 1) * 4]) = pk;
                }
            // O += P @ V ; osum += P @ ones (vf shared across both m-halves)
            __builtin_amdgcn_s_setprio(1);
            #pragma unroll
            for (int ks = 0; ks < 2; ks++) {
                int chunk = (4 * ks + lhi) ^ xr;
                bf16x8 vf[4];
                #pragma unroll
                for (int nd = 0; nd < 4; nd++)
                    vf[nd] = *(const bf16x8*)(&Vb[cur][(nd * 16 + l15) * LKK + ks * 32 + lhi * 8]);
                #pragma unroll
                for (int m = 0; m < 2; m++) {
                    bf16x8 pf = *(const bf16x8*)(&Pl[wid][m][l15 * 64 + chunk * 8]);
                    #pragma unroll
                    for (int nd = 0; nd < 4; nd++)
                        o[m][nd] = __builtin_amdgcn_mfma_f32_16x16x32_bf16(pf, vf[nd], o[m][nd], 0, 0, 0);
                    osum[m] = __builtin_amdgcn_mfma_f32_16x16x32_bf16(pf, ones, osum[m], 0, 0, 0);
                }
            }
            __builtin_amdgcn_s_setprio(0);
        }
        *(uint4*)(&Kb[cur ^ 1][r0 * LKK + c0]) = ka;
        *(uint4*)(&Vb[cur ^ 1][r0 * LKK + c0]) = va;
        __syncthreads();
        cur ^= 1;
    }
    // epilogue: osum already in O-layout (q = 4*lhi+j per m-half)
    #pragma unroll
    for (int m = 0; m < 2; m++) {
        #pragma unroll
        for (int j = 0; j < 4; j++) {
            float inv = 1.0f / osum[m][j];
            int t = qrow + m * 16 + lhi * 4 + j;
            #pragma unroll
            for (int nd = 0; nd < 4; nd++) {
                int d = nd * 16 + l15;
                attn_ws[((size_t)(b * 2048 + t) * 16 + h) * 64 + d] = f2bf(o[m][nd][j] * inv);
            }
        }
    }
}

// ---------------- Output projection GEMM (2-phase + granule swizzle, r10-proven) ----------------
__global__ __launch_bounds__(256)
void proj_gemm2(const unsigned short* __restrict__ A,
                const unsigned short* __restrict__ Bt,
                const float* __restrict__ bias, float* __restrict__ out)
{
    const int K = 1024, N = 1024;
    __shared__ unsigned short Al[2][128 * 32];
    __shared__ unsigned short Bl[2][128 * 32];
    const int tid = threadIdx.x;
    const int lane = tid & 63, w = tid >> 6;
    const int l15 = lane & 15, lhi = lane >> 4;
    const int m0 = blockIdx.x * 128, n0 = blockIdx.y * 128;
    const int wm = (w >> 1) * 64, wn = (w & 1) * 64;

    const int srow = w * 32 + (lane >> 2);
    const int sg = ((lane & 3) ^ ((lane >> 3) & 3)) * 8;
    const unsigned short* ga = A + (size_t)(m0 + srow) * K + sg;
    const unsigned short* gb = Bt + (size_t)(n0 + srow) * K + sg;
    const int lofs = w * 32 * 32;

    const int rc = (lhi ^ ((l15 >> 1) & 3)) * 8;

    f32x4 acc[4][4] = {};

    gload_lds16(ga, &Al[0][lofs]);
    gload_lds16(ga + 16 * K, &Al[0][lofs + 512]);
    gload_lds16(gb, &Bl[0][lofs]);
    gload_lds16(gb + 16 * K, &Bl[0][lofs + 512]);
    __syncthreads();

    int cur = 0;
    for (int k0 = 0; k0 < K; k0 += 32) {
        const int nxt = cur ^ 1;
        if (k0 + 32 < K) {
            gload_lds16(ga + k0 + 32,          &Al[nxt][lofs]);
            gload_lds16(ga + k0 + 32 + 16 * K, &Al[nxt][lofs + 512]);
            gload_lds16(gb + k0 + 32,          &Bl[nxt][lofs]);
            gload_lds16(gb + k0 + 32 + 16 * K, &Bl[nxt][lofs + 512]);
        }
        bf16x8 af[4], bfr[4];
        #pragma unroll
        for (int m = 0; m < 4; m++)
            af[m] = *(const bf16x8*)(&Al[cur][(wm + m * 16 + l15) * 32 + rc]);
        #pragma unroll
        for (int n = 0; n < 4; n++)
            bfr[n] = *(const bf16x8*)(&Bl[cur][(wn + n * 16 + l15) * 32 + rc]);
        __builtin_amdgcn_s_setprio(1);
        #pragma unroll
        for (int m = 0; m < 4; m++)
            #pragma unroll
            for (int n = 0; n < 4; n++)
                acc[m][n] = __builtin_amdgcn_mfma_f32_16x16x32_bf16(af[m], bfr[n], acc[m][n], 0, 0, 0);
        __builtin_amdgcn_s_setprio(0);
        __syncthreads();
        cur = nxt;
    }

    #pragma unroll
    for (int n = 0; n < 4; n++) {
        int col = n0 + wn + n * 16 + l15;
        float bv = bias[col];
        #pragma unroll
        for (int m = 0; m < 4; m++)
            #pragma unroll
            for (int j = 0; j < 4; j++) {
                int row = m0 + wm + m * 16 + lhi * 4 + j;
                out[row * N + col] = acc[m][n][j] + bv;
            }
    }
}

extern "C" void kernel_launch(void* const* d_in, const int* in_sizes, int n_in,
                              void* d_out, int out_size, void* d_ws, size_t ws_size,
                              hipStream_t stream)
{
    const float* x      = (const float*)d_in[0];
    const float* w_qkv  = (const float*)d_in[1];
    const float* b_qkv  = (const float*)d_in[2];
    const float* w_proj = (const float*)d_in[3];
    const float* b_proj = (const float*)d_in[4];
    float* out = (float*)d_out;

    const size_t SEG = (size_t)8 * 1024 * 1024;
    unsigned short* q_ws    = (unsigned short*)d_ws;
    unsigned short* k_ws    = q_ws + SEG;
    unsigned short* vT_ws   = k_ws + SEG;
    unsigned short* attn_ws = vT_ws + SEG;

    unsigned short* x_bf   = (unsigned short*)d_out;          // d_out as scratch
    unsigned short* wqkvT  = x_bf + SEG;
    unsigned short* wprojT = q_ws;                            // dead after attn

    cvt_bf16<<<4096, 256, 0, stream>>>(x, x_bf);
    transpose_w<<<dim3(16, 48), 256, 0, stream>>>(w_qkv, wqkvT, 1024, 3072);
    qkv_gemm2<<<dim3(64, 24), 256, 0, stream>>>(x_bf, wqkvT, b_qkv, q_ws, k_ws, vT_ws);
    attn_fwd<<<dim3(64, 8), 512, 0, stream>>>(q_ws, k_ws, vT_ws, attn_ws);
    transpose_w<<<dim3(16, 16), 256, 0, stream>>>(w_proj, wprojT, 1024, 1024);
    proj_gemm2<<<dim3(64, 8), 256, 0, stream>>>(attn_ws, wprojT, b_proj, out);
}

// Round 15
// 171.871 us; speedup vs baseline: 1.2417x; 1.2417x over previous
//
#include <hip/hip_runtime.h>

typedef float f32x4 __attribute__((ext_vector_type(4)));
typedef __bf16 bf16x8 __attribute__((ext_vector_type(8)));

static __device__ __forceinline__ unsigned short f2bf(float f) {
    unsigned int u = __builtin_bit_cast(unsigned int, f);
    u += 0x7fffu + ((u >> 16) & 1u);
    return (unsigned short)(u >> 16);
}
static __device__ __forceinline__ unsigned short bfc(float f) {
    return __builtin_bit_cast(unsigned short, (__bf16)f);
}

#define QSC 0.18033688011112042f   // log2(e)/sqrt(HD) folded into Q

typedef const __attribute__((address_space(1))) unsigned int gu32;
typedef __attribute__((address_space(3))) unsigned int lu32;
static __device__ __forceinline__ void gload_lds16(const unsigned short* g, unsigned short* l) {
    __builtin_amdgcn_global_load_lds((gu32*)g, (lu32*)l, 16, 0, 0);
}

// ---------------- fp32 -> bf16 elementwise convert ----------------
__global__ __launch_bounds__(256)
void cvt_bf16(const float* __restrict__ in, unsigned short* __restrict__ out) {
    int i = blockIdx.x * 256 + threadIdx.x;
    const float4* p = (const float4*)in + (size_t)i * 2;
    float4 a = p[0], b = p[1];
    union { unsigned short s[8]; uint4 v; } u;
    u.s[0] = f2bf(a.x); u.s[1] = f2bf(a.y); u.s[2] = f2bf(a.z); u.s[3] = f2bf(a.w);
    u.s[4] = f2bf(b.x); u.s[5] = f2bf(b.y); u.s[6] = f2bf(b.z); u.s[7] = f2bf(b.w);
    ((uint4*)out)[i] = u.v;
}

// ---------------- weight transpose+convert: w[K][N] fp32 -> wT[N][K] bf16 ----------------
__global__ __launch_bounds__(256)
void transpose_w(const float* __restrict__ w, unsigned short* __restrict__ wT,
                 int K, int N) {
    __shared__ unsigned short Lt[64][65];
    const int k0 = blockIdx.x * 64, n0 = blockIdx.y * 64;
    const int t = threadIdx.x;
    const int r = t >> 4, c4 = (t & 15) * 4;
    #pragma unroll
    for (int i = 0; i < 4; i++) {
        int rr = r + i * 16;
        float4 v = *(const float4*)(w + (k0 + rr) * N + n0 + c4);
        Lt[rr][c4 + 0] = f2bf(v.x); Lt[rr][c4 + 1] = f2bf(v.y);
        Lt[rr][c4 + 2] = f2bf(v.z); Lt[rr][c4 + 3] = f2bf(v.w);
    }
    __syncthreads();
    const int rn = t >> 3, ks = (t & 7) * 8;
    #pragma unroll
    for (int i = 0; i < 2; i++) {
        int rr = rn + i * 32;
        unsigned short tmp[8];
        #pragma unroll
        for (int j = 0; j < 8; j++) tmp[j] = Lt[ks + j][rr];
        *(uint4*)(wT + (n0 + rr) * K + k0 + ks) = *(const uint4*)tmp;
    }
}

// ---------------- QKV GEMM (2-phase prefetch + granule swizzle, r10-proven) ----------------
__global__ __launch_bounds__(256)
void qkv_gemm2(const unsigned short* __restrict__ A,
               const unsigned short* __restrict__ Bt,
               const float* __restrict__ bias,
               unsigned short* __restrict__ q_ws,
               unsigned short* __restrict__ k_ws,
               unsigned short* __restrict__ vT_ws)
{
    const int K = 1024;
    __shared__ unsigned short Al[2][128 * 32];
    __shared__ unsigned short Bl[2][128 * 32];
    const int tid = threadIdx.x;
    const int lane = tid & 63, w = tid >> 6;
    const int l15 = lane & 15, lhi = lane >> 4;
    const int m0 = blockIdx.x * 128, n0 = blockIdx.y * 128;
    const int wm = (w >> 1) * 64, wn = (w & 1) * 64;

    const int srow = w * 32 + (lane >> 2);
    const int sg = ((lane & 3) ^ ((lane >> 3) & 3)) * 8;
    const unsigned short* ga = A + (size_t)(m0 + srow) * K + sg;
    const unsigned short* gb = Bt + (size_t)(n0 + srow) * K + sg;
    const int lofs = w * 32 * 32;

    const int rc = (lhi ^ ((l15 >> 1) & 3)) * 8;

    f32x4 acc[4][4] = {};

    gload_lds16(ga, &Al[0][lofs]);
    gload_lds16(ga + 16 * K, &Al[0][lofs + 512]);
    gload_lds16(gb, &Bl[0][lofs]);
    gload_lds16(gb + 16 * K, &Bl[0][lofs + 512]);
    __syncthreads();

    int cur = 0;
    for (int k0 = 0; k0 < K; k0 += 32) {
        const int nxt = cur ^ 1;
        if (k0 + 32 < K) {
            gload_lds16(ga + k0 + 32,          &Al[nxt][lofs]);
            gload_lds16(ga + k0 + 32 + 16 * K, &Al[nxt][lofs + 512]);
            gload_lds16(gb + k0 + 32,          &Bl[nxt][lofs]);
            gload_lds16(gb + k0 + 32 + 16 * K, &Bl[nxt][lofs + 512]);
        }
        bf16x8 af[4], bfr[4];
        #pragma unroll
        for (int m = 0; m < 4; m++)
            af[m] = *(const bf16x8*)(&Al[cur][(wm + m * 16 + l15) * 32 + rc]);
        #pragma unroll
        for (int n = 0; n < 4; n++)
            bfr[n] = *(const bf16x8*)(&Bl[cur][(wn + n * 16 + l15) * 32 + rc]);
        __builtin_amdgcn_s_setprio(1);
        #pragma unroll
        for (int m = 0; m < 4; m++)
            #pragma unroll
            for (int n = 0; n < 4; n++)
                acc[m][n] = __builtin_amdgcn_mfma_f32_16x16x32_bf16(af[m], bfr[n], acc[m][n], 0, 0, 0);
        __builtin_amdgcn_s_setprio(0);
        __syncthreads();
        cur = nxt;
    }

    #pragma unroll
    for (int n = 0; n < 4; n++) {
        int col = n0 + wn + n * 16 + l15;
        float bv = bias[col];
        int which = col >> 10;          // 0=Q 1=K 2=V (wave/block-uniform per n)
        int d = col & 1023;
        int h = d >> 6, hd = d & 63;
        if (which == 2) {
            // V: pack 4 consecutive t per lane -> ushort4 store (write-combines to ~1x)
            #pragma unroll
            for (int m = 0; m < 4; m++) {
                int row0 = m0 + wm + m * 16 + lhi * 4;
                int b = row0 >> 11, t0 = row0 & 2047;
                ushort4 pk;
                pk.x = f2bf(acc[m][n][0] + bv);
                pk.y = f2bf(acc[m][n][1] + bv);
                pk.z = f2bf(acc[m][n][2] + bv);
                pk.w = f2bf(acc[m][n][3] + bv);
                *(ushort4*)(&vT_ws[((size_t)(b * 16 + h) * 64 + hd) * 2048 + t0]) = pk;
            }
        } else {
            #pragma unroll
            for (int m = 0; m < 4; m++) {
                #pragma unroll
                for (int j = 0; j < 4; j++) {
                    int row = m0 + wm + m * 16 + lhi * 4 + j;
                    int b = row >> 11, t = row & 2047;
                    float val = acc[m][n][j] + bv;
                    int bh = b * 16 + h;
                    if (which == 0) q_ws[(bh * 2048 + t) * 64 + hd] = f2bf(val * QSC);
                    else            k_ws[(bh * 2048 + t) * 64 + hd] = f2bf(val);
                }
            }
        }
    }
}

// ---------------- Flash attention (causal) ----------------
// m=2 amortization at spill-free geometry: 4 waves x 32 q-rows (QB=128),
// __launch_bounds__(256,2) -> 256-VGPR cap (r14's 128-cap spilled: WRITE_SIZE
// 16->110MB). Paired q-blocks {15-p, p} => exactly 34 kv-tiles/block.
// K/V frags read once per wave serve 2 row-halves -> LDS traffic per q-row halves.
// No-max softmax (r13-proven), osum via MFMA ones-column.
#define LKK 72

__global__ __launch_bounds__(256, 2)
void attn_fwd(const unsigned short* __restrict__ q_ws,
              const unsigned short* __restrict__ k_ws,
              const unsigned short* __restrict__ vT_ws,
              unsigned short* __restrict__ attn_ws)
{
    __shared__ unsigned short Kb[2][64 * LKK];      // 18 KB
    __shared__ unsigned short Vb[2][64 * LKK];      // 18 KB
    __shared__ unsigned short Pl[4][2][16 * 64];    // 16 KB  (total 52 KB -> 3 blocks/CU)

    const int bh = blockIdx.x;
    const int p  = blockIdx.y;
    const int b = bh >> 4, h = bh & 15;
    const int tid = threadIdx.x;
    const int lane = tid & 63, wid = tid >> 6;   // 4 waves
    const int l15 = lane & 15, lhi = lane >> 4;
    const int tbase = bh * 2048;
    const float NINF = -__builtin_inff();

    const int r0 = tid >> 2;            // 0..63 staging row (4 threads/row)
    const int c0 = (tid & 3) * 16;      // elem col 0,16,32,48 (2 x 16B each)
    const unsigned short* kg = k_ws + (size_t)(tbase + r0) * 64 + c0;
    const unsigned short* vg = vT_ws + ((size_t)bh * 64 + r0) * 2048 + c0;

    const int xr = l15 & 7;

    bf16x8 ones;
    #pragma unroll
    for (int z = 0; z < 8; z++) ones[z] = (__bf16)1.0f;

    #pragma unroll 1
    for (int seg = 0; seg < 2; ++seg) {
        const int qb = seg ? p : 15 - p;
        const int qrow = qb * 128 + wid * 32;     // wave owns rows qrow..qrow+31
        const int nkv = 2 * (qb + 1);

        bf16x8 qf[2][2];
        #pragma unroll
        for (int m = 0; m < 2; m++)
            #pragma unroll
            for (int ks = 0; ks < 2; ks++)
                qf[m][ks] = *(const bf16x8*)(q_ws + (size_t)(tbase + qrow + m * 16 + l15) * 64 + ks * 32 + lhi * 8);

        f32x4 o[2][4] = {};
        f32x4 osum[2] = {};

        // prologue: stage tile 0 into buffer 0 (32B/thread per operand)
        *(uint4*)(&Kb[0][r0 * LKK + c0])     = *(const uint4*)(kg);
        *(uint4*)(&Kb[0][r0 * LKK + c0 + 8]) = *(const uint4*)(kg + 8);
        *(uint4*)(&Vb[0][r0 * LKK + c0])     = *(const uint4*)(vg);
        *(uint4*)(&Vb[0][r0 * LKK + c0 + 8]) = *(const uint4*)(vg + 8);
        __syncthreads();

        int cur = 0;
        for (int kb = 0; kb < nkv; ++kb) {
            const int k0 = kb * 64;
            const int knx = (kb + 1 < nkv ? kb + 1 : kb) * 64;
            uint4 ka0 = *(const uint4*)(kg + (size_t)knx * 64);
            uint4 ka1 = *(const uint4*)(kg + (size_t)knx * 64 + 8);
            uint4 va0 = *(const uint4*)(vg + knx);
            uint4 va1 = *(const uint4*)(vg + knx + 8);

            if (k0 <= qrow + 31) {
                // S^T = K Q^T : q = l15 (per m-half), k = 16n + 4*lhi + j
                f32x4 s[2][4] = {};
                __builtin_amdgcn_s_setprio(1);
                #pragma unroll
                for (int ks = 0; ks < 2; ks++) {
                    bf16x8 kf[4];
                    #pragma unroll
                    for (int n = 0; n < 4; n++)
                        kf[n] = *(const bf16x8*)(&Kb[cur][(n * 16 + l15) * LKK + ks * 32 + lhi * 8]);
                    #pragma unroll
                    for (int m = 0; m < 2; m++)
                        #pragma unroll
                        for (int n = 0; n < 4; n++)
                            s[m][n] = __builtin_amdgcn_mfma_f32_16x16x32_bf16(kf[n], qf[m][ks], s[m][n], 0, 0, 0);
                }
                __builtin_amdgcn_s_setprio(0);
                // causal mask: only tiles crossing the diagonal
                if (k0 + 63 > qrow) {
                    #pragma unroll
                    for (int m = 0; m < 2; m++) {
                        int qg = qrow + m * 16 + l15;
                        #pragma unroll
                        for (int n = 0; n < 4; n++) {
                            int kgl = k0 + n * 16 + lhi * 4;
                            #pragma unroll
                            for (int j = 0; j < 4; j++)
                                s[m][n][j] = (kgl + j <= qg) ? s[m][n][j] : NINF;
                        }
                    }
                }
                // un-subtracted softmax: p = 2^s (masked -> 0)
                #pragma unroll
                for (int m = 0; m < 2; m++)
                    #pragma unroll
                    for (int n = 0; n < 4; n++)
                        #pragma unroll
                        for (int j = 0; j < 4; j++)
                            s[m][n][j] = exp2f(s[m][n][j]);
                // P -> LDS, swizzled 8B writes
                #pragma unroll
                for (int m = 0; m < 2; m++)
                    #pragma unroll
                    for (int n = 0; n < 4; n++) {
                        ushort4 pk;
                        pk.x = bfc(s[m][n][0]); pk.y = bfc(s[m][n][1]);
                        pk.z = bfc(s[m][n][2]); pk.w = bfc(s[m][n][3]);
                        int chunk = (2 * n + (lhi >> 1)) ^ xr;
                        *(ushort4*)(&Pl[wid][m][l15 * 64 + chunk * 8 + (lhi & 1) * 4]) = pk;
                    }
                // O += P @ V ; osum += P @ ones (vf shared across both m-halves)
                __builtin_amdgcn_s_setprio(1);
                #pragma unroll
                for (int ks = 0; ks < 2; ks++) {
                    int chunk = (4 * ks + lhi) ^ xr;
                    bf16x8 vf[4];
                    #pragma unroll
                    for (int nd = 0; nd < 4; nd++)
                        vf[nd] = *(const bf16x8*)(&Vb[cur][(nd * 16 + l15) * LKK + ks * 32 + lhi * 8]);
                    #pragma unroll
                    for (int m = 0; m < 2; m++) {
                        bf16x8 pf = *(const bf16x8*)(&Pl[wid][m][l15 * 64 + chunk * 8]);
                        #pragma unroll
                        for (int nd = 0; nd < 4; nd++)
                            o[m][nd] = __builtin_amdgcn_mfma_f32_16x16x32_bf16(pf, vf[nd], o[m][nd], 0, 0, 0);
                        osum[m] = __builtin_amdgcn_mfma_f32_16x16x32_bf16(pf, ones, osum[m], 0, 0, 0);
                    }
                }
                __builtin_amdgcn_s_setprio(0);
            }
            *(uint4*)(&Kb[cur ^ 1][r0 * LKK + c0])     = ka0;
            *(uint4*)(&Kb[cur ^ 1][r0 * LKK + c0 + 8]) = ka1;
            *(uint4*)(&Vb[cur ^ 1][r0 * LKK + c0])     = va0;
            *(uint4*)(&Vb[cur ^ 1][r0 * LKK + c0 + 8]) = va1;
            __syncthreads();
            cur ^= 1;
        }
        // epilogue: osum already in O-layout (q = 4*lhi+j per m-half)
        #pragma unroll
        for (int m = 0; m < 2; m++) {
            #pragma unroll
            for (int j = 0; j < 4; j++) {
                float inv = 1.0f / osum[m][j];
                int t = qrow + m * 16 + lhi * 4 + j;
                #pragma unroll
                for (int nd = 0; nd < 4; nd++) {
                    int d = nd * 16 + l15;
                    attn_ws[((size_t)(b * 2048 + t) * 16 + h) * 64 + d] = f2bf(o[m][nd][j] * inv);
                }
            }
        }
    }
}

// ---------------- Output projection GEMM (2-phase + granule swizzle, r10-proven) ----------------
__global__ __launch_bounds__(256)
void proj_gemm2(const unsigned short* __restrict__ A,
                const unsigned short* __restrict__ Bt,
                const float* __restrict__ bias, float* __restrict__ out)
{
    const int K = 1024, N = 1024;
    __shared__ unsigned short Al[2][128 * 32];
    __shared__ unsigned short Bl[2][128 * 32];
    const int tid = threadIdx.x;
    const int lane = tid & 63, w = tid >> 6;
    const int l15 = lane & 15, lhi = lane >> 4;
    const int m0 = blockIdx.x * 128, n0 = blockIdx.y * 128;
    const int wm = (w >> 1) * 64, wn = (w & 1) * 64;

    const int srow = w * 32 + (lane >> 2);
    const int sg = ((lane & 3) ^ ((lane >> 3) & 3)) * 8;
    const unsigned short* ga = A + (size_t)(m0 + srow) * K + sg;
    const unsigned short* gb = Bt + (size_t)(n0 + srow) * K + sg;
    const int lofs = w * 32 * 32;

    const int rc = (lhi ^ ((l15 >> 1) & 3)) * 8;

    f32x4 acc[4][4] = {};

    gload_lds16(ga, &Al[0][lofs]);
    gload_lds16(ga + 16 * K, &Al[0][lofs + 512]);
    gload_lds16(gb, &Bl[0][lofs]);
    gload_lds16(gb + 16 * K, &Bl[0][lofs + 512]);
    __syncthreads();

    int cur = 0;
    for (int k0 = 0; k0 < K; k0 += 32) {
        const int nxt = cur ^ 1;
        if (k0 + 32 < K) {
            gload_lds16(ga + k0 + 32,          &Al[nxt][lofs]);
            gload_lds16(ga + k0 + 32 + 16 * K, &Al[nxt][lofs + 512]);
            gload_lds16(gb + k0 + 32,          &Bl[nxt][lofs]);
            gload_lds16(gb + k0 + 32 + 16 * K, &Bl[nxt][lofs + 512]);
        }
        bf16x8 af[4], bfr[4];
        #pragma unroll
        for (int m = 0; m < 4; m++)
            af[m] = *(const bf16x8*)(&Al[cur][(wm + m * 16 + l15) * 32 + rc]);
        #pragma unroll
        for (int n = 0; n < 4; n++)
            bfr[n] = *(const bf16x8*)(&Bl[cur][(wn + n * 16 + l15) * 32 + rc]);
        __builtin_amdgcn_s_setprio(1);
        #pragma unroll
        for (int m = 0; m < 4; m++)
            #pragma unroll
            for (int n = 0; n < 4; n++)
                acc[m][n] = __builtin_amdgcn_mfma_f32_16x16x32_bf16(af[m], bfr[n], acc[m][n], 0, 0, 0);
        __builtin_amdgcn_s_setprio(0);
        __syncthreads();
        cur = nxt;
    }

    #pragma unroll
    for (int n = 0; n < 4; n++) {
        int col = n0 + wn + n * 16 + l15;
        float bv = bias[col];
        #pragma unroll
        for (int m = 0; m < 4; m++)
            #pragma unroll
            for (int j = 0; j < 4; j++) {
                int row = m0 + wm + m * 16 + lhi * 4 + j;
                out[row * N + col] = acc[m][n][j] + bv;
            }
    }
}

extern "C" void kernel_launch(void* const* d_in, const int* in_sizes, int n_in,
                              void* d_out, int out_size, void* d_ws, size_t ws_size,
                              hipStream_t stream)
{
    const float* x      = (const float*)d_in[0];
    const float* w_qkv  = (const float*)d_in[1];
    const float* b_qkv  = (const float*)d_in[2];
    const float* w_proj = (const float*)d_in[3];
    const float* b_proj = (const float*)d_in[4];
    float* out = (float*)d_out;

    const size_t SEG = (size_t)8 * 1024 * 1024;
    unsigned short* q_ws    = (unsigned short*)d_ws;
    unsigned short* k_ws    = q_ws + SEG;
    unsigned short* vT_ws   = k_ws + SEG;
    unsigned short* attn_ws = vT_ws + SEG;

    unsigned short* x_bf   = (unsigned short*)d_out;          // d_out as scratch
    unsigned short* wqkvT  = x_bf + SEG;
    unsigned short* wprojT = q_ws;                            // dead after attn

    cvt_bf16<<<4096, 256, 0, stream>>>(x, x_bf);
    transpose_w<<<dim3(16, 48), 256, 0, stream>>>(w_qkv, wqkvT, 1024, 3072);
    qkv_gemm2<<<dim3(64, 24), 256, 0, stream>>>(x_bf, wqkvT, b_qkv, q_ws, k_ws, vT_ws);
    attn_fwd<<<dim3(64, 8), 256, 0, stream>>>(q_ws, k_ws, vT_ws, attn_ws);
    transpose_w<<<dim3(16, 16), 256, 0, stream>>>(w_proj, wprojT, 1024, 1024);
    proj_gemm2<<<dim3(64, 8), 256, 0, stream>>>(attn_ws, wprojT, b_proj, out);
}

// Round 16
// 166.581 us; speedup vs baseline: 1.2811x; 1.0318x over previous
//
#include <hip/hip_runtime.h>

typedef float f32x4 __attribute__((ext_vector_type(4)));
typedef __bf16 bf16x8 __attribute__((ext_vector_type(8)));

static __device__ __forceinline__ unsigned short f2bf(float f) {
    unsigned int u = __builtin_bit_cast(unsigned int, f);
    u += 0x7fffu + ((u >> 16) & 1u);
    return (unsigned short)(u >> 16);
}
static __device__ __forceinline__ unsigned short bfc(float f) {
    return __builtin_bit_cast(unsigned short, (__bf16)f);
}

#define QSC 0.18033688011112042f   // log2(e)/sqrt(HD) folded into Q

typedef const __attribute__((address_space(1))) unsigned int gu32;
typedef __attribute__((address_space(3))) unsigned int lu32;
static __device__ __forceinline__ void gload_lds16(const unsigned short* g, unsigned short* l) {
    __builtin_amdgcn_global_load_lds((gu32*)g, (lu32*)l, 16, 0, 0);
}

// ---------------- fp32 -> bf16 elementwise convert ----------------
__global__ __launch_bounds__(256)
void cvt_bf16(const float* __restrict__ in, unsigned short* __restrict__ out) {
    int i = blockIdx.x * 256 + threadIdx.x;
    const float4* p = (const float4*)in + (size_t)i * 2;
    float4 a = p[0], b = p[1];
    union { unsigned short s[8]; uint4 v; } u;
    u.s[0] = f2bf(a.x); u.s[1] = f2bf(a.y); u.s[2] = f2bf(a.z); u.s[3] = f2bf(a.w);
    u.s[4] = f2bf(b.x); u.s[5] = f2bf(b.y); u.s[6] = f2bf(b.z); u.s[7] = f2bf(b.w);
    ((uint4*)out)[i] = u.v;
}

// ---------------- weight transpose+convert: w[K][N] fp32 -> wT[N][K] bf16 ----------------
__global__ __launch_bounds__(256)
void transpose_w(const float* __restrict__ w, unsigned short* __restrict__ wT,
                 int K, int N) {
    __shared__ unsigned short Lt[64][65];
    const int k0 = blockIdx.x * 64, n0 = blockIdx.y * 64;
    const int t = threadIdx.x;
    const int r = t >> 4, c4 = (t & 15) * 4;
    #pragma unroll
    for (int i = 0; i < 4; i++) {
        int rr = r + i * 16;
        float4 v = *(const float4*)(w + (k0 + rr) * N + n0 + c4);
        Lt[rr][c4 + 0] = f2bf(v.x); Lt[rr][c4 + 1] = f2bf(v.y);
        Lt[rr][c4 + 2] = f2bf(v.z); Lt[rr][c4 + 3] = f2bf(v.w);
    }
    __syncthreads();
    const int rn = t >> 3, ks = (t & 7) * 8;
    #pragma unroll
    for (int i = 0; i < 2; i++) {
        int rr = rn + i * 32;
        unsigned short tmp[8];
        #pragma unroll
        for (int j = 0; j < 8; j++) tmp[j] = Lt[ks + j][rr];
        *(uint4*)(wT + (n0 + rr) * K + k0 + ks) = *(const uint4*)tmp;
    }
}

// ---------------- QKV GEMM (2-phase prefetch + granule swizzle) ----------------
// Epilogue: Q/K blocks bounce C through the (dead) staging LDS to emit fully
// coalesced 16B stores (scalar 2B scatter was ~2x HBM write amplification).
__global__ __launch_bounds__(256)
void qkv_gemm2(const unsigned short* __restrict__ A,
               const unsigned short* __restrict__ Bt,
               const float* __restrict__ bias,
               unsigned short* __restrict__ q_ws,
               unsigned short* __restrict__ k_ws,
               unsigned short* __restrict__ vT_ws)
{
    const int K = 1024;
    __shared__ unsigned short LD[16384];   // Al[2][4096] | Bl[2][4096]; reused as 128x128 bounce
    const int tid = threadIdx.x;
    const int lane = tid & 63, w = tid >> 6;
    const int l15 = lane & 15, lhi = lane >> 4;
    const int m0 = blockIdx.x * 128, n0 = blockIdx.y * 128;
    const int wm = (w >> 1) * 64, wn = (w & 1) * 64;

    const int srow = w * 32 + (lane >> 2);
    const int sg = ((lane & 3) ^ ((lane >> 3) & 3)) * 8;
    const unsigned short* ga = A + (size_t)(m0 + srow) * K + sg;
    const unsigned short* gb = Bt + (size_t)(n0 + srow) * K + sg;
    const int lofs = w * 32 * 32;

    const int rc = (lhi ^ ((l15 >> 1) & 3)) * 8;

    #define ALp(c) (LD + (c) * 4096)
    #define BLp(c) (LD + 8192 + (c) * 4096)

    f32x4 acc[4][4] = {};

    gload_lds16(ga, ALp(0) + lofs);
    gload_lds16(ga + 16 * K, ALp(0) + lofs + 512);
    gload_lds16(gb, BLp(0) + lofs);
    gload_lds16(gb + 16 * K, BLp(0) + lofs + 512);
    __syncthreads();

    int cur = 0;
    for (int k0 = 0; k0 < K; k0 += 32) {
        const int nxt = cur ^ 1;
        if (k0 + 32 < K) {
            gload_lds16(ga + k0 + 32,          ALp(nxt) + lofs);
            gload_lds16(ga + k0 + 32 + 16 * K, ALp(nxt) + lofs + 512);
            gload_lds16(gb + k0 + 32,          BLp(nxt) + lofs);
            gload_lds16(gb + k0 + 32 + 16 * K, BLp(nxt) + lofs + 512);
        }
        bf16x8 af[4], bfr[4];
        #pragma unroll
        for (int m = 0; m < 4; m++)
            af[m] = *(const bf16x8*)(ALp(cur) + (wm + m * 16 + l15) * 32 + rc);
        #pragma unroll
        for (int n = 0; n < 4; n++)
            bfr[n] = *(const bf16x8*)(BLp(cur) + (wn + n * 16 + l15) * 32 + rc);
        __builtin_amdgcn_s_setprio(1);
        #pragma unroll
        for (int m = 0; m < 4; m++)
            #pragma unroll
            for (int n = 0; n < 4; n++)
                acc[m][n] = __builtin_amdgcn_mfma_f32_16x16x32_bf16(af[m], bfr[n], acc[m][n], 0, 0, 0);
        __builtin_amdgcn_s_setprio(0);
        __syncthreads();
        cur = nxt;
    }

    const int which = n0 >> 10;          // block-uniform: 0=Q 1=K 2=V
    if (which == 2) {
        // V: packed ushort4 along t into [bh][d][t]  (r12-proven, ~1x writes)
        #pragma unroll
        for (int n = 0; n < 4; n++) {
            int col = n0 + wn + n * 16 + l15;
            float bv = bias[col];
            int d = col & 1023;
            int h = d >> 6, hd = d & 63;
            #pragma unroll
            for (int m = 0; m < 4; m++) {
                int row0 = m0 + wm + m * 16 + lhi * 4;
                int b = row0 >> 11, t0 = row0 & 2047;
                ushort4 pk;
                pk.x = f2bf(acc[m][n][0] + bv);
                pk.y = f2bf(acc[m][n][1] + bv);
                pk.z = f2bf(acc[m][n][2] + bv);
                pk.w = f2bf(acc[m][n][3] + bv);
                *(ushort4*)(&vT_ws[((size_t)(b * 16 + h) * 64 + hd) * 2048 + t0]) = pk;
            }
        }
    } else {
        // Q/K: bounce through LDS -> coalesced 16B stores into [bh][t][hd]
        const float qs = (which == 0) ? QSC : 1.0f;
        unsigned short* q_or_k = (which == 0) ? q_ws : k_ws;
        __syncthreads();   // staging buffers dead; safe to overwrite
        #pragma unroll
        for (int n = 0; n < 4; n++) {
            int col = wn + n * 16 + l15;             // col within 128-tile
            float bv = bias[n0 + col];
            #pragma unroll
            for (int m = 0; m < 4; m++) {
                #pragma unroll
                for (int j = 0; j < 4; j++) {
                    int r = wm + m * 16 + lhi * 4 + j;
                    LD[r * 128 + col] = f2bf((acc[m][n][j] + bv) * qs);
                }
            }
        }
        __syncthreads();
        const int cbase = n0 & 1023;
        #pragma unroll
        for (int i = 0; i < 8; i++) {
            int e = i * 256 + tid;        // 2048 chunks: r = e>>4, ch = e&15
            int r = e >> 4, c = (e & 15) * 8;
            uint4 v = *(const uint4*)(&LD[r * 128 + c]);
            int grow = m0 + r;
            int b = grow >> 11, t = grow & 2047;
            int gc = cbase + c;
            int h = gc >> 6, hd = gc & 63;
            *(uint4*)(&q_or_k[((size_t)(b * 16 + h) * 2048 + t) * 64 + hd]) = v;
        }
    }
    #undef ALp
    #undef BLp
}

// ---------------- Flash attention (causal) ----------------
// m=2 amortization at spill-free geometry (r15-proven): 4 waves x 32 q-rows,
// paired q-blocks {15-p, p}; no-max softmax; osum via MFMA ones-column.
#define LKK 72

__global__ __launch_bounds__(256, 2)
void attn_fwd(const unsigned short* __restrict__ q_ws,
              const unsigned short* __restrict__ k_ws,
              const unsigned short* __restrict__ vT_ws,
              unsigned short* __restrict__ attn_ws)
{
    __shared__ unsigned short Kb[2][64 * LKK];
    __shared__ unsigned short Vb[2][64 * LKK];
    __shared__ unsigned short Pl[4][2][16 * 64];

    const int bh = blockIdx.x;
    const int p  = blockIdx.y;
    const int b = bh >> 4, h = bh & 15;
    const int tid = threadIdx.x;
    const int lane = tid & 63, wid = tid >> 6;
    const int l15 = lane & 15, lhi = lane >> 4;
    const int tbase = bh * 2048;
    const float NINF = -__builtin_inff();

    const int r0 = tid >> 2;
    const int c0 = (tid & 3) * 16;
    const unsigned short* kg = k_ws + (size_t)(tbase + r0) * 64 + c0;
    const unsigned short* vg = vT_ws + ((size_t)bh * 64 + r0) * 2048 + c0;

    const int xr = l15 & 7;

    bf16x8 ones;
    #pragma unroll
    for (int z = 0; z < 8; z++) ones[z] = (__bf16)1.0f;

    #pragma unroll 1
    for (int seg = 0; seg < 2; ++seg) {
        const int qb = seg ? p : 15 - p;
        const int qrow = qb * 128 + wid * 32;
        const int nkv = 2 * (qb + 1);

        bf16x8 qf[2][2];
        #pragma unroll
        for (int m = 0; m < 2; m++)
            #pragma unroll
            for (int ks = 0; ks < 2; ks++)
                qf[m][ks] = *(const bf16x8*)(q_ws + (size_t)(tbase + qrow + m * 16 + l15) * 64 + ks * 32 + lhi * 8);

        f32x4 o[2][4] = {};
        f32x4 osum[2] = {};

        *(uint4*)(&Kb[0][r0 * LKK + c0])     = *(const uint4*)(kg);
        *(uint4*)(&Kb[0][r0 * LKK + c0 + 8]) = *(const uint4*)(kg + 8);
        *(uint4*)(&Vb[0][r0 * LKK + c0])     = *(const uint4*)(vg);
        *(uint4*)(&Vb[0][r0 * LKK + c0 + 8]) = *(const uint4*)(vg + 8);
        __syncthreads();

        int cur = 0;
        for (int kb = 0; kb < nkv; ++kb) {
            const int k0 = kb * 64;
            const int knx = (kb + 1 < nkv ? kb + 1 : kb) * 64;
            uint4 ka0 = *(const uint4*)(kg + (size_t)knx * 64);
            uint4 ka1 = *(const uint4*)(kg + (size_t)knx * 64 + 8);
            uint4 va0 = *(const uint4*)(vg + knx);
            uint4 va1 = *(const uint4*)(vg + knx + 8);

            if (k0 <= qrow + 31) {
                f32x4 s[2][4] = {};
                __builtin_amdgcn_s_setprio(1);
                #pragma unroll
                for (int ks = 0; ks < 2; ks++) {
                    bf16x8 kf[4];
                    #pragma unroll
                    for (int n = 0; n < 4; n++)
                        kf[n] = *(const bf16x8*)(&Kb[cur][(n * 16 + l15) * LKK + ks * 32 + lhi * 8]);
                    #pragma unroll
                    for (int m = 0; m < 2; m++)
                        #pragma unroll
                        for (int n = 0; n < 4; n++)
                            s[m][n] = __builtin_amdgcn_mfma_f32_16x16x32_bf16(kf[n], qf[m][ks], s[m][n], 0, 0, 0);
                }
                __builtin_amdgcn_s_setprio(0);
                if (k0 + 63 > qrow) {
                    #pragma unroll
                    for (int m = 0; m < 2; m++) {
                        int qg = qrow + m * 16 + l15;
                        #pragma unroll
                        for (int n = 0; n < 4; n++) {
                            int kgl = k0 + n * 16 + lhi * 4;
                            #pragma unroll
                            for (int j = 0; j < 4; j++)
                                s[m][n][j] = (kgl + j <= qg) ? s[m][n][j] : NINF;
                        }
                    }
                }
                #pragma unroll
                for (int m = 0; m < 2; m++)
                    #pragma unroll
                    for (int n = 0; n < 4; n++)
                        #pragma unroll
                        for (int j = 0; j < 4; j++)
                            s[m][n][j] = exp2f(s[m][n][j]);
                #pragma unroll
                for (int m = 0; m < 2; m++)
                    #pragma unroll
                    for (int n = 0; n < 4; n++) {
                        ushort4 pk;
                        pk.x = bfc(s[m][n][0]); pk.y = bfc(s[m][n][1]);
                        pk.z = bfc(s[m][n][2]); pk.w = bfc(s[m][n][3]);
                        int chunk = (2 * n + (lhi >> 1)) ^ xr;
                        *(ushort4*)(&Pl[wid][m][l15 * 64 + chunk * 8 + (lhi & 1) * 4]) = pk;
                    }
                __builtin_amdgcn_s_setprio(1);
                #pragma unroll
                for (int ks = 0; ks < 2; ks++) {
                    int chunk = (4 * ks + lhi) ^ xr;
                    bf16x8 vf[4];
                    #pragma unroll
                    for (int nd = 0; nd < 4; nd++)
                        vf[nd] = *(const bf16x8*)(&Vb[cur][(nd * 16 + l15) * LKK + ks * 32 + lhi * 8]);
                    #pragma unroll
                    for (int m = 0; m < 2; m++) {
                        bf16x8 pf = *(const bf16x8*)(&Pl[wid][m][l15 * 64 + chunk * 8]);
                        #pragma unroll
                        for (int nd = 0; nd < 4; nd++)
                            o[m][nd] = __builtin_amdgcn_mfma_f32_16x16x32_bf16(pf, vf[nd], o[m][nd], 0, 0, 0);
                        osum[m] = __builtin_amdgcn_mfma_f32_16x16x32_bf16(pf, ones, osum[m], 0, 0, 0);
                    }
                }
                __builtin_amdgcn_s_setprio(0);
            }
            *(uint4*)(&Kb[cur ^ 1][r0 * LKK + c0])     = ka0;
            *(uint4*)(&Kb[cur ^ 1][r0 * LKK + c0 + 8]) = ka1;
            *(uint4*)(&Vb[cur ^ 1][r0 * LKK + c0])     = va0;
            *(uint4*)(&Vb[cur ^ 1][r0 * LKK + c0 + 8]) = va1;
            __syncthreads();
            cur ^= 1;
        }
        #pragma unroll
        for (int m = 0; m < 2; m++) {
            #pragma unroll
            for (int j = 0; j < 4; j++) {
                float inv = 1.0f / osum[m][j];
                int t = qrow + m * 16 + lhi * 4 + j;
                #pragma unroll
                for (int nd = 0; nd < 4; nd++) {
                    int d = nd * 16 + l15;
                    attn_ws[((size_t)(b * 2048 + t) * 16 + h) * 64 + d] = f2bf(o[m][nd][j] * inv);
                }
            }
        }
    }
}

// ---------------- Output projection GEMM (2-phase + granule swizzle, r10-proven) ----------------
__global__ __launch_bounds__(256)
void proj_gemm2(const unsigned short* __restrict__ A,
                const unsigned short* __restrict__ Bt,
                const float* __restrict__ bias, float* __restrict__ out)
{
    const int K = 1024, N = 1024;
    __shared__ unsigned short Al[2][128 * 32];
    __shared__ unsigned short Bl[2][128 * 32];
    const int tid = threadIdx.x;
    const int lane = tid & 63, w = tid >> 6;
    const int l15 = lane & 15, lhi = lane >> 4;
    const int m0 = blockIdx.x * 128, n0 = blockIdx.y * 128;
    const int wm = (w >> 1) * 64, wn = (w & 1) * 64;

    const int srow = w * 32 + (lane >> 2);
    const int sg = ((lane & 3) ^ ((lane >> 3) & 3)) * 8;
    const unsigned short* ga = A + (size_t)(m0 + srow) * K + sg;
    const unsigned short* gb = Bt + (size_t)(n0 + srow) * K + sg;
    const int lofs = w * 32 * 32;

    const int rc = (lhi ^ ((l15 >> 1) & 3)) * 8;

    f32x4 acc[4][4] = {};

    gload_lds16(ga, &Al[0][lofs]);
    gload_lds16(ga + 16 * K, &Al[0][lofs + 512]);
    gload_lds16(gb, &Bl[0][lofs]);
    gload_lds16(gb + 16 * K, &Bl[0][lofs + 512]);
    __syncthreads();

    int cur = 0;
    for (int k0 = 0; k0 < K; k0 += 32) {
        const int nxt = cur ^ 1;
        if (k0 + 32 < K) {
            gload_lds16(ga + k0 + 32,          &Al[nxt][lofs]);
            gload_lds16(ga + k0 + 32 + 16 * K, &Al[nxt][lofs + 512]);
            gload_lds16(gb + k0 + 32,          &Bl[nxt][lofs]);
            gload_lds16(gb + k0 + 32 + 16 * K, &Bl[nxt][lofs + 512]);
        }
        bf16x8 af[4], bfr[4];
        #pragma unroll
        for (int m = 0; m < 4; m++)
            af[m] = *(const bf16x8*)(&Al[cur][(wm + m * 16 + l15) * 32 + rc]);
        #pragma unroll
        for (int n = 0; n < 4; n++)
            bfr[n] = *(const bf16x8*)(&Bl[cur][(wn + n * 16 + l15) * 32 + rc]);
        __builtin_amdgcn_s_setprio(1);
        #pragma unroll
        for (int m = 0; m < 4; m++)
            #pragma unroll
            for (int n = 0; n < 4; n++)
                acc[m][n] = __builtin_amdgcn_mfma_f32_16x16x32_bf16(af[m], bfr[n], acc[m][n], 0, 0, 0);
        __builtin_amdgcn_s_setprio(0);
        __syncthreads();
        cur = nxt;
    }

    #pragma unroll
    for (int n = 0; n < 4; n++) {
        int col = n0 + wn + n * 16 + l15;
        float bv = bias[col];
        #pragma unroll
        for (int m = 0; m < 4; m++)
            #pragma unroll
            for (int j = 0; j < 4; j++) {
                int row = m0 + wm + m * 16 + lhi * 4 + j;
                out[row * N + col] = acc[m][n][j] + bv;
            }
    }
}

extern "C" void kernel_launch(void* const* d_in, const int* in_sizes, int n_in,
                              void* d_out, int out_size, void* d_ws, size_t ws_size,
                              hipStream_t stream)
{
    const float* x      = (const float*)d_in[0];
    const float* w_qkv  = (const float*)d_in[1];
    const float* b_qkv  = (const float*)d_in[2];
    const float* w_proj = (const float*)d_in[3];
    const float* b_proj = (const float*)d_in[4];
    float* out = (float*)d_out;

    const size_t SEG = (size_t)8 * 1024 * 1024;
    unsigned short* q_ws    = (unsigned short*)d_ws;
    unsigned short* k_ws    = q_ws + SEG;
    unsigned short* vT_ws   = k_ws + SEG;
    unsigned short* attn_ws = vT_ws + SEG;

    unsigned short* x_bf   = (unsigned short*)d_out;          // d_out as scratch
    unsigned short* wqkvT  = x_bf + SEG;
    unsigned short* wprojT = q_ws;                            // dead after attn

    cvt_bf16<<<4096, 256, 0, stream>>>(x, x_bf);
    transpose_w<<<dim3(16, 48), 256, 0, stream>>>(w_qkv, wqkvT, 1024, 3072);
    qkv_gemm2<<<dim3(64, 24), 256, 0, stream>>>(x_bf, wqkvT, b_qkv, q_ws, k_ws, vT_ws);
    attn_fwd<<<dim3(64, 8), 256, 0, stream>>>(q_ws, k_ws, vT_ws, attn_ws);
    transpose_w<<<dim3(16, 16), 256, 0, stream>>>(w_proj, wprojT, 1024, 1024);
    proj_gemm2<<<dim3(64, 8), 256, 0, stream>>>(attn_ws, wprojT, b_proj, out);
}

// Round 17
// 165.360 us; speedup vs baseline: 1.2906x; 1.0074x over previous
//
#include <hip/hip_runtime.h>

typedef float f32x4 __attribute__((ext_vector_type(4)));
typedef __bf16 bf16x8 __attribute__((ext_vector_type(8)));

static __device__ __forceinline__ unsigned short f2bf(float f) {
    unsigned int u = __builtin_bit_cast(unsigned int, f);
    u += 0x7fffu + ((u >> 16) & 1u);
    return (unsigned short)(u >> 16);
}
static __device__ __forceinline__ unsigned short bfc(float f) {
    return __builtin_bit_cast(unsigned short, (__bf16)f);
}

#define QSC 0.18033688011112042f   // log2(e)/sqrt(HD) folded into Q

typedef const __attribute__((address_space(1))) unsigned int gu32;
typedef __attribute__((address_space(3))) unsigned int lu32;
static __device__ __forceinline__ void gload_lds16(const unsigned short* g, unsigned short* l) {
    __builtin_amdgcn_global_load_lds((gu32*)g, (lu32*)l, 16, 0, 0);
}

// ---------------- fp32 -> bf16 elementwise convert ----------------
__global__ __launch_bounds__(256)
void cvt_bf16(const float* __restrict__ in, unsigned short* __restrict__ out) {
    int i = blockIdx.x * 256 + threadIdx.x;
    const float4* p = (const float4*)in + (size_t)i * 2;
    float4 a = p[0], b = p[1];
    union { unsigned short s[8]; uint4 v; } u;
    u.s[0] = f2bf(a.x); u.s[1] = f2bf(a.y); u.s[2] = f2bf(a.z); u.s[3] = f2bf(a.w);
    u.s[4] = f2bf(b.x); u.s[5] = f2bf(b.y); u.s[6] = f2bf(b.z); u.s[7] = f2bf(b.w);
    ((uint4*)out)[i] = u.v;
}

// ---------------- weight transpose+convert: w[K][N] fp32 -> wT[N][K] bf16 ----------------
__global__ __launch_bounds__(256)
void transpose_w(const float* __restrict__ w, unsigned short* __restrict__ wT,
                 int K, int N) {
    __shared__ unsigned short Lt[64][65];
    const int k0 = blockIdx.x * 64, n0 = blockIdx.y * 64;
    const int t = threadIdx.x;
    const int r = t >> 4, c4 = (t & 15) * 4;
    #pragma unroll
    for (int i = 0; i < 4; i++) {
        int rr = r + i * 16;
        float4 v = *(const float4*)(w + (k0 + rr) * N + n0 + c4);
        Lt[rr][c4 + 0] = f2bf(v.x); Lt[rr][c4 + 1] = f2bf(v.y);
        Lt[rr][c4 + 2] = f2bf(v.z); Lt[rr][c4 + 3] = f2bf(v.w);
    }
    __syncthreads();
    const int rn = t >> 3, ks = (t & 7) * 8;
    #pragma unroll
    for (int i = 0; i < 2; i++) {
        int rr = rn + i * 32;
        unsigned short tmp[8];
        #pragma unroll
        for (int j = 0; j < 8; j++) tmp[j] = Lt[ks + j][rr];
        *(uint4*)(wT + (n0 + rr) * K + k0 + ks) = *(const uint4*)tmp;
    }
}

// ---------------- QKV GEMM (2-phase prefetch + granule swizzle + LDS-bounce epilogue) ----------------
__global__ __launch_bounds__(256)
void qkv_gemm2(const unsigned short* __restrict__ A,
               const unsigned short* __restrict__ Bt,
               const float* __restrict__ bias,
               unsigned short* __restrict__ q_ws,
               unsigned short* __restrict__ k_ws,
               unsigned short* __restrict__ vT_ws)
{
    const int K = 1024;
    __shared__ unsigned short LD[16384];   // Al[2][4096] | Bl[2][4096]; reused as 128x128 bounce
    const int tid = threadIdx.x;
    const int lane = tid & 63, w = tid >> 6;
    const int l15 = lane & 15, lhi = lane >> 4;
    const int m0 = blockIdx.x * 128, n0 = blockIdx.y * 128;
    const int wm = (w >> 1) * 64, wn = (w & 1) * 64;

    const int srow = w * 32 + (lane >> 2);
    const int sg = ((lane & 3) ^ ((lane >> 3) & 3)) * 8;
    const unsigned short* ga = A + (size_t)(m0 + srow) * K + sg;
    const unsigned short* gb = Bt + (size_t)(n0 + srow) * K + sg;
    const int lofs = w * 32 * 32;

    const int rc = (lhi ^ ((l15 >> 1) & 3)) * 8;

    #define ALp(c) (LD + (c) * 4096)
    #define BLp(c) (LD + 8192 + (c) * 4096)

    f32x4 acc[4][4] = {};

    gload_lds16(ga, ALp(0) + lofs);
    gload_lds16(ga + 16 * K, ALp(0) + lofs + 512);
    gload_lds16(gb, BLp(0) + lofs);
    gload_lds16(gb + 16 * K, BLp(0) + lofs + 512);
    __syncthreads();

    int cur = 0;
    for (int k0 = 0; k0 < K; k0 += 32) {
        const int nxt = cur ^ 1;
        if (k0 + 32 < K) {
            gload_lds16(ga + k0 + 32,          ALp(nxt) + lofs);
            gload_lds16(ga + k0 + 32 + 16 * K, ALp(nxt) + lofs + 512);
            gload_lds16(gb + k0 + 32,          BLp(nxt) + lofs);
            gload_lds16(gb + k0 + 32 + 16 * K, BLp(nxt) + lofs + 512);
        }
        bf16x8 af[4], bfr[4];
        #pragma unroll
        for (int m = 0; m < 4; m++)
            af[m] = *(const bf16x8*)(ALp(cur) + (wm + m * 16 + l15) * 32 + rc);
        #pragma unroll
        for (int n = 0; n < 4; n++)
            bfr[n] = *(const bf16x8*)(BLp(cur) + (wn + n * 16 + l15) * 32 + rc);
        __builtin_amdgcn_s_setprio(1);
        #pragma unroll
        for (int m = 0; m < 4; m++)
            #pragma unroll
            for (int n = 0; n < 4; n++)
                acc[m][n] = __builtin_amdgcn_mfma_f32_16x16x32_bf16(af[m], bfr[n], acc[m][n], 0, 0, 0);
        __builtin_amdgcn_s_setprio(0);
        __syncthreads();
        cur = nxt;
    }

    const int which = n0 >> 10;          // block-uniform: 0=Q 1=K 2=V
    if (which == 2) {
        #pragma unroll
        for (int n = 0; n < 4; n++) {
            int col = n0 + wn + n * 16 + l15;
            float bv = bias[col];
            int d = col & 1023;
            int h = d >> 6, hd = d & 63;
            #pragma unroll
            for (int m = 0; m < 4; m++) {
                int row0 = m0 + wm + m * 16 + lhi * 4;
                int b = row0 >> 11, t0 = row0 & 2047;
                ushort4 pk;
                pk.x = f2bf(acc[m][n][0] + bv);
                pk.y = f2bf(acc[m][n][1] + bv);
                pk.z = f2bf(acc[m][n][2] + bv);
                pk.w = f2bf(acc[m][n][3] + bv);
                *(ushort4*)(&vT_ws[((size_t)(b * 16 + h) * 64 + hd) * 2048 + t0]) = pk;
            }
        }
    } else {
        const float qs = (which == 0) ? QSC : 1.0f;
        unsigned short* q_or_k = (which == 0) ? q_ws : k_ws;
        __syncthreads();
        #pragma unroll
        for (int n = 0; n < 4; n++) {
            int col = wn + n * 16 + l15;
            float bv = bias[n0 + col];
            #pragma unroll
            for (int m = 0; m < 4; m++) {
                #pragma unroll
                for (int j = 0; j < 4; j++) {
                    int r = wm + m * 16 + lhi * 4 + j;
                    LD[r * 128 + col] = f2bf((acc[m][n][j] + bv) * qs);
                }
            }
        }
        __syncthreads();
        const int cbase = n0 & 1023;
        #pragma unroll
        for (int i = 0; i < 8; i++) {
            int e = i * 256 + tid;
            int r = e >> 4, c = (e & 15) * 8;
            uint4 v = *(const uint4*)(&LD[r * 128 + c]);
            int grow = m0 + r;
            int b = grow >> 11, t = grow & 2047;
            int gc = cbase + c;
            int h = gc >> 6, hd = gc & 63;
            *(uint4*)(&q_or_k[((size_t)(b * 16 + h) * 2048 + t) * 64 + hd]) = v;
        }
    }
    #undef ALp
    #undef BLp
}

// ---------------- Flash attention (causal) ----------------
// Unpaired q-blocks: grid 64x16, one 128-row q-block per block, qb = 15 - y
// (longest blocks dispatch first, LPT). 52KB LDS -> 3 blocks/CU resident
// (vs 2 with pairing) -> more independent streams to cover the per-tile
// dependency chain. m=2 amortization, no-max softmax, osum via MFMA ones.
#define LKK 72

__global__ __launch_bounds__(256, 2)
void attn_fwd(const unsigned short* __restrict__ q_ws,
              const unsigned short* __restrict__ k_ws,
              const unsigned short* __restrict__ vT_ws,
              unsigned short* __restrict__ attn_ws)
{
    __shared__ unsigned short Kb[2][64 * LKK];
    __shared__ unsigned short Vb[2][64 * LKK];
    __shared__ unsigned short Pl[4][2][16 * 64];

    const int bh = blockIdx.x;
    const int qb = 15 - blockIdx.y;            // descending: long blocks first
    const int b = bh >> 4, h = bh & 15;
    const int tid = threadIdx.x;
    const int lane = tid & 63, wid = tid >> 6;
    const int l15 = lane & 15, lhi = lane >> 4;
    const int tbase = bh * 2048;
    const float NINF = -__builtin_inff();

    const int r0 = tid >> 2;
    const int c0 = (tid & 3) * 16;
    const unsigned short* kg = k_ws + (size_t)(tbase + r0) * 64 + c0;
    const unsigned short* vg = vT_ws + ((size_t)bh * 64 + r0) * 2048 + c0;

    const int xr = l15 & 7;

    bf16x8 ones;
    #pragma unroll
    for (int z = 0; z < 8; z++) ones[z] = (__bf16)1.0f;

    const int qrow = qb * 128 + wid * 32;
    const int nkv = 2 * (qb + 1);

    bf16x8 qf[2][2];
    #pragma unroll
    for (int m = 0; m < 2; m++)
        #pragma unroll
        for (int ks = 0; ks < 2; ks++)
            qf[m][ks] = *(const bf16x8*)(q_ws + (size_t)(tbase + qrow + m * 16 + l15) * 64 + ks * 32 + lhi * 8);

    f32x4 o[2][4] = {};
    f32x4 osum[2] = {};

    *(uint4*)(&Kb[0][r0 * LKK + c0])     = *(const uint4*)(kg);
    *(uint4*)(&Kb[0][r0 * LKK + c0 + 8]) = *(const uint4*)(kg + 8);
    *(uint4*)(&Vb[0][r0 * LKK + c0])     = *(const uint4*)(vg);
    *(uint4*)(&Vb[0][r0 * LKK + c0 + 8]) = *(const uint4*)(vg + 8);
    __syncthreads();

    int cur = 0;
    for (int kb = 0; kb < nkv; ++kb) {
        const int k0 = kb * 64;
        const int knx = (kb + 1 < nkv ? kb + 1 : kb) * 64;
        uint4 ka0 = *(const uint4*)(kg + (size_t)knx * 64);
        uint4 ka1 = *(const uint4*)(kg + (size_t)knx * 64 + 8);
        uint4 va0 = *(const uint4*)(vg + knx);
        uint4 va1 = *(const uint4*)(vg + knx + 8);

        if (k0 <= qrow + 31) {
            f32x4 s[2][4] = {};
            __builtin_amdgcn_s_setprio(1);
            #pragma unroll
            for (int ks = 0; ks < 2; ks++) {
                bf16x8 kf[4];
                #pragma unroll
                for (int n = 0; n < 4; n++)
                    kf[n] = *(const bf16x8*)(&Kb[cur][(n * 16 + l15) * LKK + ks * 32 + lhi * 8]);
                #pragma unroll
                for (int m = 0; m < 2; m++)
                    #pragma unroll
                    for (int n = 0; n < 4; n++)
                        s[m][n] = __builtin_amdgcn_mfma_f32_16x16x32_bf16(kf[n], qf[m][ks], s[m][n], 0, 0, 0);
            }
            __builtin_amdgcn_s_setprio(0);
            if (k0 + 63 > qrow) {
                #pragma unroll
                for (int m = 0; m < 2; m++) {
                    int qg = qrow + m * 16 + l15;
                    #pragma unroll
                    for (int n = 0; n < 4; n++) {
                        int kgl = k0 + n * 16 + lhi * 4;
                        #pragma unroll
                        for (int j = 0; j < 4; j++)
                            s[m][n][j] = (kgl + j <= qg) ? s[m][n][j] : NINF;
                    }
                }
            }
            #pragma unroll
            for (int m = 0; m < 2; m++)
                #pragma unroll
                for (int n = 0; n < 4; n++)
                    #pragma unroll
                    for (int j = 0; j < 4; j++)
                        s[m][n][j] = exp2f(s[m][n][j]);
            #pragma unroll
            for (int m = 0; m < 2; m++)
                #pragma unroll
                for (int n = 0; n < 4; n++) {
                    ushort4 pk;
                    pk.x = bfc(s[m][n][0]); pk.y = bfc(s[m][n][1]);
                    pk.z = bfc(s[m][n][2]); pk.w = bfc(s[m][n][3]);
                    int chunk = (2 * n + (lhi >> 1)) ^ xr;
                    *(ushort4*)(&Pl[wid][m][l15 * 64 + chunk * 8 + (lhi & 1) * 4]) = pk;
                }
            __builtin_amdgcn_s_setprio(1);
            #pragma unroll
            for (int ks = 0; ks < 2; ks++) {
                int chunk = (4 * ks + lhi) ^ xr;
                bf16x8 vf[4];
                #pragma unroll
                for (int nd = 0; nd < 4; nd++)
                    vf[nd] = *(const bf16x8*)(&Vb[cur][(nd * 16 + l15) * LKK + ks * 32 + lhi * 8]);
                #pragma unroll
                for (int m = 0; m < 2; m++) {
                    bf16x8 pf = *(const bf16x8*)(&Pl[wid][m][l15 * 64 + chunk * 8]);
                    #pragma unroll
                    for (int nd = 0; nd < 4; nd++)
                        o[m][nd] = __builtin_amdgcn_mfma_f32_16x16x32_bf16(pf, vf[nd], o[m][nd], 0, 0, 0);
                    osum[m] = __builtin_amdgcn_mfma_f32_16x16x32_bf16(pf, ones, osum[m], 0, 0, 0);
                }
            }
            __builtin_amdgcn_s_setprio(0);
        }
        *(uint4*)(&Kb[cur ^ 1][r0 * LKK + c0])     = ka0;
        *(uint4*)(&Kb[cur ^ 1][r0 * LKK + c0 + 8]) = ka1;
        *(uint4*)(&Vb[cur ^ 1][r0 * LKK + c0])     = va0;
        *(uint4*)(&Vb[cur ^ 1][r0 * LKK + c0 + 8]) = va1;
        __syncthreads();
        cur ^= 1;
    }
    #pragma unroll
    for (int m = 0; m < 2; m++) {
        #pragma unroll
        for (int j = 0; j < 4; j++) {
            float inv = 1.0f / osum[m][j];
            int t = qrow + m * 16 + lhi * 4 + j;
            #pragma unroll
            for (int nd = 0; nd < 4; nd++) {
                int d = nd * 16 + l15;
                attn_ws[((size_t)(b * 2048 + t) * 16 + h) * 64 + d] = f2bf(o[m][nd][j] * inv);
            }
        }
    }
}

// ---------------- Output projection GEMM (2-phase + granule swizzle, r10-proven) ----------------
__global__ __launch_bounds__(256)
void proj_gemm2(const unsigned short* __restrict__ A,
                const unsigned short* __restrict__ Bt,
                const float* __restrict__ bias, float* __restrict__ out)
{
    const int K = 1024, N = 1024;
    __shared__ unsigned short Al[2][128 * 32];
    __shared__ unsigned short Bl[2][128 * 32];
    const int tid = threadIdx.x;
    const int lane = tid & 63, w = tid >> 6;
    const int l15 = lane & 15, lhi = lane >> 4;
    const int m0 = blockIdx.x * 128, n0 = blockIdx.y * 128;
    const int wm = (w >> 1) * 64, wn = (w & 1) * 64;

    const int srow = w * 32 + (lane >> 2);
    const int sg = ((lane & 3) ^ ((lane >> 3) & 3)) * 8;
    const unsigned short* ga = A + (size_t)(m0 + srow) * K + sg;
    const unsigned short* gb = Bt + (size_t)(n0 + srow) * K + sg;
    const int lofs = w * 32 * 32;

    const int rc = (lhi ^ ((l15 >> 1) & 3)) * 8;

    f32x4 acc[4][4] = {};

    gload_lds16(ga, &Al[0][lofs]);
    gload_lds16(ga + 16 * K, &Al[0][lofs + 512]);
    gload_lds16(gb, &Bl[0][lofs]);
    gload_lds16(gb + 16 * K, &Bl[0][lofs + 512]);
    __syncthreads();

    int cur = 0;
    for (int k0 = 0; k0 < K; k0 += 32) {
        const int nxt = cur ^ 1;
        if (k0 + 32 < K) {
            gload_lds16(ga + k0 + 32,          &Al[nxt][lofs]);
            gload_lds16(ga + k0 + 32 + 16 * K, &Al[nxt][lofs + 512]);
            gload_lds16(gb + k0 + 32,          &Bl[nxt][lofs]);
            gload_lds16(gb + k0 + 32 + 16 * K, &Bl[nxt][lofs + 512]);
        }
        bf16x8 af[4], bfr[4];
        #pragma unroll
        for (int m = 0; m < 4; m++)
            af[m] = *(const bf16x8*)(&Al[cur][(wm + m * 16 + l15) * 32 + rc]);
        #pragma unroll
        for (int n = 0; n < 4; n++)
            bfr[n] = *(const bf16x8*)(&Bl[cur][(wn + n * 16 + l15) * 32 + rc]);
        __builtin_amdgcn_s_setprio(1);
        #pragma unroll
        for (int m = 0; m < 4; m++)
            #pragma unroll
            for (int n = 0; n < 4; n++)
                acc[m][n] = __builtin_amdgcn_mfma_f32_16x16x32_bf16(af[m], bfr[n], acc[m][n], 0, 0, 0);
        __builtin_amdgcn_s_setprio(0);
        __syncthreads();
        cur = nxt;
    }

    #pragma unroll
    for (int n = 0; n < 4; n++) {
        int col = n0 + wn + n * 16 + l15;
        float bv = bias[col];
        #pragma unroll
        for (int m = 0; m < 4; m++)
            #pragma unroll
            for (int j = 0; j < 4; j++) {
                int row = m0 + wm + m * 16 + lhi * 4 + j;
                out[row * N + col] = acc[m][n][j] + bv;
            }
    }
}

extern "C" void kernel_launch(void* const* d_in, const int* in_sizes, int n_in,
                              void* d_out, int out_size, void* d_ws, size_t ws_size,
                              hipStream_t stream)
{
    const float* x      = (const float*)d_in[0];
    const float* w_qkv  = (const float*)d_in[1];
    const float* b_qkv  = (const float*)d_in[2];
    const float* w_proj = (const float*)d_in[3];
    const float* b_proj = (const float*)d_in[4];
    float* out = (float*)d_out;

    const size_t SEG = (size_t)8 * 1024 * 1024;
    unsigned short* q_ws    = (unsigned short*)d_ws;
    unsigned short* k_ws    = q_ws + SEG;
    unsigned short* vT_ws   = k_ws + SEG;
    unsigned short* attn_ws = vT_ws + SEG;

    unsigned short* x_bf   = (unsigned short*)d_out;          // d_out as scratch
    unsigned short* wqkvT  = x_bf + SEG;
    unsigned short* wprojT = q_ws;                            // dead after attn

    cvt_bf16<<<4096, 256, 0, stream>>>(x, x_bf);
    transpose_w<<<dim3(16, 48), 256, 0, stream>>>(w_qkv, wqkvT, 1024, 3072);
    qkv_gemm2<<<dim3(64, 24), 256, 0, stream>>>(x_bf, wqkvT, b_qkv, q_ws, k_ws, vT_ws);
    attn_fwd<<<dim3(64, 16), 256, 0, stream>>>(q_ws, k_ws, vT_ws, attn_ws);
    transpose_w<<<dim3(16, 16), 256, 0, stream>>>(w_proj, wprojT, 1024, 1024);
    proj_gemm2<<<dim3(64, 8), 256, 0, stream>>>(attn_ws, wprojT, b_proj, out);
}

// Round 18
// 165.193 us; speedup vs baseline: 1.2919x; 1.0010x over previous
//
#include <hip/hip_runtime.h>

typedef float f32x4 __attribute__((ext_vector_type(4)));
typedef __bf16 bf16x8 __attribute__((ext_vector_type(8)));

static __device__ __forceinline__ unsigned short f2bf(float f) {
    unsigned int u = __builtin_bit_cast(unsigned int, f);
    u += 0x7fffu + ((u >> 16) & 1u);
    return (unsigned short)(u >> 16);
}
static __device__ __forceinline__ unsigned short bfc(float f) {
    return __builtin_bit_cast(unsigned short, (__bf16)f);
}

#define QSC 0.18033688011112042f   // log2(e)/sqrt(HD) folded into Q

typedef const __attribute__((address_space(1))) unsigned int gu32;
typedef __attribute__((address_space(3))) unsigned int lu32;
static __device__ __forceinline__ void gload_lds16(const unsigned short* g, unsigned short* l) {
    __builtin_amdgcn_global_load_lds((gu32*)g, (lu32*)l, 16, 0, 0);
}

// ---------------- fp32 -> bf16 elementwise convert ----------------
__global__ __launch_bounds__(256)
void cvt_bf16(const float* __restrict__ in, unsigned short* __restrict__ out) {
    int i = blockIdx.x * 256 + threadIdx.x;
    const float4* p = (const float4*)in + (size_t)i * 2;
    float4 a = p[0], b = p[1];
    union { unsigned short s[8]; uint4 v; } u;
    u.s[0] = f2bf(a.x); u.s[1] = f2bf(a.y); u.s[2] = f2bf(a.z); u.s[3] = f2bf(a.w);
    u.s[4] = f2bf(b.x); u.s[5] = f2bf(b.y); u.s[6] = f2bf(b.z); u.s[7] = f2bf(b.w);
    ((uint4*)out)[i] = u.v;
}

// ---------------- weight transpose+convert: w[K][N] fp32 -> wT[N][K] bf16 ----------------
__global__ __launch_bounds__(256)
void transpose_w(const float* __restrict__ w, unsigned short* __restrict__ wT,
                 int K, int N) {
    __shared__ unsigned short Lt[64][65];
    const int k0 = blockIdx.x * 64, n0 = blockIdx.y * 64;
    const int t = threadIdx.x;
    const int r = t >> 4, c4 = (t & 15) * 4;
    #pragma unroll
    for (int i = 0; i < 4; i++) {
        int rr = r + i * 16;
        float4 v = *(const float4*)(w + (k0 + rr) * N + n0 + c4);
        Lt[rr][c4 + 0] = f2bf(v.x); Lt[rr][c4 + 1] = f2bf(v.y);
        Lt[rr][c4 + 2] = f2bf(v.z); Lt[rr][c4 + 3] = f2bf(v.w);
    }
    __syncthreads();
    const int rn = t >> 3, ks = (t & 7) * 8;
    #pragma unroll
    for (int i = 0; i < 2; i++) {
        int rr = rn + i * 32;
        unsigned short tmp[8];
        #pragma unroll
        for (int j = 0; j < 8; j++) tmp[j] = Lt[ks + j][rr];
        *(uint4*)(wT + (n0 + rr) * K + k0 + ks) = *(const uint4*)tmp;
    }
}

// ---------------- QKV GEMM (2-phase prefetch + granule swizzle + LDS-bounce epilogue) ----------------
__global__ __launch_bounds__(256)
void qkv_gemm2(const unsigned short* __restrict__ A,
               const unsigned short* __restrict__ Bt,
               const float* __restrict__ bias,
               unsigned short* __restrict__ q_ws,
               unsigned short* __restrict__ k_ws,
               unsigned short* __restrict__ vT_ws)
{
    const int K = 1024;
    __shared__ unsigned short LD[16384];   // Al[2][4096] | Bl[2][4096]; reused as 128x128 bounce
    const int tid = threadIdx.x;
    const int lane = tid & 63, w = tid >> 6;
    const int l15 = lane & 15, lhi = lane >> 4;
    const int m0 = blockIdx.x * 128, n0 = blockIdx.y * 128;
    const int wm = (w >> 1) * 64, wn = (w & 1) * 64;

    const int srow = w * 32 + (lane >> 2);
    const int sg = ((lane & 3) ^ ((lane >> 3) & 3)) * 8;
    const unsigned short* ga = A + (size_t)(m0 + srow) * K + sg;
    const unsigned short* gb = Bt + (size_t)(n0 + srow) * K + sg;
    const int lofs = w * 32 * 32;

    const int rc = (lhi ^ ((l15 >> 1) & 3)) * 8;

    #define ALp(c) (LD + (c) * 4096)
    #define BLp(c) (LD + 8192 + (c) * 4096)

    f32x4 acc[4][4] = {};

    gload_lds16(ga, ALp(0) + lofs);
    gload_lds16(ga + 16 * K, ALp(0) + lofs + 512);
    gload_lds16(gb, BLp(0) + lofs);
    gload_lds16(gb + 16 * K, BLp(0) + lofs + 512);
    __syncthreads();

    int cur = 0;
    for (int k0 = 0; k0 < K; k0 += 32) {
        const int nxt = cur ^ 1;
        if (k0 + 32 < K) {
            gload_lds16(ga + k0 + 32,          ALp(nxt) + lofs);
            gload_lds16(ga + k0 + 32 + 16 * K, ALp(nxt) + lofs + 512);
            gload_lds16(gb + k0 + 32,          BLp(nxt) + lofs);
            gload_lds16(gb + k0 + 32 + 16 * K, BLp(nxt) + lofs + 512);
        }
        bf16x8 af[4], bfr[4];
        #pragma unroll
        for (int m = 0; m < 4; m++)
            af[m] = *(const bf16x8*)(ALp(cur) + (wm + m * 16 + l15) * 32 + rc);
        #pragma unroll
        for (int n = 0; n < 4; n++)
            bfr[n] = *(const bf16x8*)(BLp(cur) + (wn + n * 16 + l15) * 32 + rc);
        __builtin_amdgcn_s_setprio(1);
        #pragma unroll
        for (int m = 0; m < 4; m++)
            #pragma unroll
            for (int n = 0; n < 4; n++)
                acc[m][n] = __builtin_amdgcn_mfma_f32_16x16x32_bf16(af[m], bfr[n], acc[m][n], 0, 0, 0);
        __builtin_amdgcn_s_setprio(0);
        __syncthreads();
        cur = nxt;
    }

    const int which = n0 >> 10;          // block-uniform: 0=Q 1=K 2=V
    if (which == 2) {
        #pragma unroll
        for (int n = 0; n < 4; n++) {
            int col = n0 + wn + n * 16 + l15;
            float bv = bias[col];
            int d = col & 1023;
            int h = d >> 6, hd = d & 63;
            #pragma unroll
            for (int m = 0; m < 4; m++) {
                int row0 = m0 + wm + m * 16 + lhi * 4;
                int b = row0 >> 11, t0 = row0 & 2047;
                ushort4 pk;
                pk.x = f2bf(acc[m][n][0] + bv);
                pk.y = f2bf(acc[m][n][1] + bv);
                pk.z = f2bf(acc[m][n][2] + bv);
                pk.w = f2bf(acc[m][n][3] + bv);
                *(ushort4*)(&vT_ws[((size_t)(b * 16 + h) * 64 + hd) * 2048 + t0]) = pk;
            }
        }
    } else {
        const float qs = (which == 0) ? QSC : 1.0f;
        unsigned short* q_or_k = (which == 0) ? q_ws : k_ws;
        __syncthreads();
        #pragma unroll
        for (int n = 0; n < 4; n++) {
            int col = wn + n * 16 + l15;
            float bv = bias[n0 + col];
            #pragma unroll
            for (int m = 0; m < 4; m++) {
                #pragma unroll
                for (int j = 0; j < 4; j++) {
                    int r = wm + m * 16 + lhi * 4 + j;
                    LD[r * 128 + col] = f2bf((acc[m][n][j] + bv) * qs);
                }
            }
        }
        __syncthreads();
        const int cbase = n0 & 1023;
        #pragma unroll
        for (int i = 0; i < 8; i++) {
            int e = i * 256 + tid;
            int r = e >> 4, c = (e & 15) * 8;
            uint4 v = *(const uint4*)(&LD[r * 128 + c]);
            int grow = m0 + r;
            int b = grow >> 11, t = grow & 2047;
            int gc = cbase + c;
            int h = gc >> 6, hd = gc & 63;
            *(uint4*)(&q_or_k[((size_t)(b * 16 + h) * 2048 + t) * 64 + hd]) = v;
        }
    }
    #undef ALp
    #undef BLp
}

// ---------------- Flash attention (causal) ----------------
// Unpaired q-blocks: grid 64x16, one 128-row q-block per block, qb = 15 - y
// (longest blocks dispatch first, LPT). 52KB LDS -> 3 blocks/CU resident
// (vs 2 with pairing) -> more independent streams to cover the per-tile
// dependency chain. m=2 amortization, no-max softmax, osum via MFMA ones.
#define LKK 72

__global__ __launch_bounds__(256, 2)
void attn_fwd(const unsigned short* __restrict__ q_ws,
              const unsigned short* __restrict__ k_ws,
              const unsigned short* __restrict__ vT_ws,
              unsigned short* __restrict__ attn_ws)
{
    __shared__ unsigned short Kb[2][64 * LKK];
    __shared__ unsigned short Vb[2][64 * LKK];
    __shared__ unsigned short Pl[4][2][16 * 64];

    const int bh = blockIdx.x;
    const int qb = 15 - blockIdx.y;            // descending: long blocks first
    const int b = bh >> 4, h = bh & 15;
    const int tid = threadIdx.x;
    const int lane = tid & 63, wid = tid >> 6;
    const int l15 = lane & 15, lhi = lane >> 4;
    const int tbase = bh * 2048;
    const float NINF = -__builtin_inff();

    const int r0 = tid >> 2;
    const int c0 = (tid & 3) * 16;
    const unsigned short* kg = k_ws + (size_t)(tbase + r0) * 64 + c0;
    const unsigned short* vg = vT_ws + ((size_t)bh * 64 + r0) * 2048 + c0;

    const int xr = l15 & 7;

    bf16x8 ones;
    #pragma unroll
    for (int z = 0; z < 8; z++) ones[z] = (__bf16)1.0f;

    const int qrow = qb * 128 + wid * 32;
    const int nkv = 2 * (qb + 1);

    bf16x8 qf[2][2];
    #pragma unroll
    for (int m = 0; m < 2; m++)
        #pragma unroll
        for (int ks = 0; ks < 2; ks++)
            qf[m][ks] = *(const bf16x8*)(q_ws + (size_t)(tbase + qrow + m * 16 + l15) * 64 + ks * 32 + lhi * 8);

    f32x4 o[2][4] = {};
    f32x4 osum[2] = {};

    *(uint4*)(&Kb[0][r0 * LKK + c0])     = *(const uint4*)(kg);
    *(uint4*)(&Kb[0][r0 * LKK + c0 + 8]) = *(const uint4*)(kg + 8);
    *(uint4*)(&Vb[0][r0 * LKK + c0])     = *(const uint4*)(vg);
    *(uint4*)(&Vb[0][r0 * LKK + c0 + 8]) = *(const uint4*)(vg + 8);
    __syncthreads();

    int cur = 0;
    for (int kb = 0; kb < nkv; ++kb) {
        const int k0 = kb * 64;
        const int knx = (kb + 1 < nkv ? kb + 1 : kb) * 64;
        uint4 ka0 = *(const uint4*)(kg + (size_t)knx * 64);
        uint4 ka1 = *(const uint4*)(kg + (size_t)knx * 64 + 8);
        uint4 va0 = *(const uint4*)(vg + knx);
        uint4 va1 = *(const uint4*)(vg + knx + 8);

        if (k0 <= qrow + 31) {
            f32x4 s[2][4] = {};
            __builtin_amdgcn_s_setprio(1);
            #pragma unroll
            for (int ks = 0; ks < 2; ks++) {
                bf16x8 kf[4];
                #pragma unroll
                for (int n = 0; n < 4; n++)
                    kf[n] = *(const bf16x8*)(&Kb[cur][(n * 16 + l15) * LKK + ks * 32 + lhi * 8]);
                #pragma unroll
                for (int m = 0; m < 2; m++)
                    #pragma unroll
                    for (int n = 0; n < 4; n++)
                        s[m][n] = __builtin_amdgcn_mfma_f32_16x16x32_bf16(kf[n], qf[m][ks], s[m][n], 0, 0, 0);
            }
            __builtin_amdgcn_s_setprio(0);
            if (k0 + 63 > qrow) {
                #pragma unroll
                for (int m = 0; m < 2; m++) {
                    int qg = qrow + m * 16 + l15;
                    #pragma unroll
                    for (int n = 0; n < 4; n++) {
                        int kgl = k0 + n * 16 + lhi * 4;
                        #pragma unroll
                        for (int j = 0; j < 4; j++)
                            s[m][n][j] = (kgl + j <= qg) ? s[m][n][j] : NINF;
                    }
                }
            }
            #pragma unroll
            for (int m = 0; m < 2; m++)
                #pragma unroll
                for (int n = 0; n < 4; n++)
                    #pragma unroll
                    for (int j = 0; j < 4; j++)
                        s[m][n][j] = exp2f(s[m][n][j]);
            #pragma unroll
            for (int m = 0; m < 2; m++)
                #pragma unroll
                for (int n = 0; n < 4; n++) {
                    ushort4 pk;
                    pk.x = bfc(s[m][n][0]); pk.y = bfc(s[m][n][1]);
                    pk.z = bfc(s[m][n][2]); pk.w = bfc(s[m][n][3]);
                    int chunk = (2 * n + (lhi >> 1)) ^ xr;
                    *(ushort4*)(&Pl[wid][m][l15 * 64 + chunk * 8 + (lhi & 1) * 4]) = pk;
                }
            __builtin_amdgcn_s_setprio(1);
            #pragma unroll
            for (int ks = 0; ks < 2; ks++) {
                int chunk = (4 * ks + lhi) ^ xr;
                bf16x8 vf[4];
                #pragma unroll
                for (int nd = 0; nd < 4; nd++)
                    vf[nd] = *(const bf16x8*)(&Vb[cur][(nd * 16 + l15) * LKK + ks * 32 + lhi * 8]);
                #pragma unroll
                for (int m = 0; m < 2; m++) {
                    bf16x8 pf = *(const bf16x8*)(&Pl[wid][m][l15 * 64 + chunk * 8]);
                    #pragma unroll
                    for (int nd = 0; nd < 4; nd++)
                        o[m][nd] = __builtin_amdgcn_mfma_f32_16x16x32_bf16(pf, vf[nd], o[m][nd], 0, 0, 0);
                    osum[m] = __builtin_amdgcn_mfma_f32_16x16x32_bf16(pf, ones, osum[m], 0, 0, 0);
                }
            }
            __builtin_amdgcn_s_setprio(0);
        }
        *(uint4*)(&Kb[cur ^ 1][r0 * LKK + c0])     = ka0;
        *(uint4*)(&Kb[cur ^ 1][r0 * LKK + c0 + 8]) = ka1;
        *(uint4*)(&Vb[cur ^ 1][r0 * LKK + c0])     = va0;
        *(uint4*)(&Vb[cur ^ 1][r0 * LKK + c0 + 8]) = va1;
        __syncthreads();
        cur ^= 1;
    }
    #pragma unroll
    for (int m = 0; m < 2; m++) {
        #pragma unroll
        for (int j = 0; j < 4; j++) {
            float inv = 1.0f / osum[m][j];
            int t = qrow + m * 16 + lhi * 4 + j;
            #pragma unroll
            for (int nd = 0; nd < 4; nd++) {
                int d = nd * 16 + l15;
                attn_ws[((size_t)(b * 2048 + t) * 16 + h) * 64 + d] = f2bf(o[m][nd][j] * inv);
            }
        }
    }
}

// ---------------- Output projection GEMM (2-phase + granule swizzle, r10-proven) ----------------
__global__ __launch_bounds__(256)
void proj_gemm2(const unsigned short* __restrict__ A,
                const unsigned short* __restrict__ Bt,
                const float* __restrict__ bias, float* __restrict__ out)
{
    const int K = 1024, N = 1024;
    __shared__ unsigned short Al[2][128 * 32];
    __shared__ unsigned short Bl[2][128 * 32];
    const int tid = threadIdx.x;
    const int lane = tid & 63, w = tid >> 6;
    const int l15 = lane & 15, lhi = lane >> 4;
    const int m0 = blockIdx.x * 128, n0 = blockIdx.y * 128;
    const int wm = (w >> 1) * 64, wn = (w & 1) * 64;

    const int srow = w * 32 + (lane >> 2);
    const int sg = ((lane & 3) ^ ((lane >> 3) & 3)) * 8;
    const unsigned short* ga = A + (size_t)(m0 + srow) * K + sg;
    const unsigned short* gb = Bt + (size_t)(n0 + srow) * K + sg;
    const int lofs = w * 32 * 32;

    const int rc = (lhi ^ ((l15 >> 1) & 3)) * 8;

    f32x4 acc[4][4] = {};

    gload_lds16(ga, &Al[0][lofs]);
    gload_lds16(ga + 16 * K, &Al[0][lofs + 512]);
    gload_lds16(gb, &Bl[0][lofs]);
    gload_lds16(gb + 16 * K, &Bl[0][lofs + 512]);
    __syncthreads();

    int cur = 0;
    for (int k0 = 0; k0 < K; k0 += 32) {
        const int nxt = cur ^ 1;
        if (k0 + 32 < K) {
            gload_lds16(ga + k0 + 32,          &Al[nxt][lofs]);
            gload_lds16(ga + k0 + 32 + 16 * K, &Al[nxt][lofs + 512]);
            gload_lds16(gb + k0 + 32,          &Bl[nxt][lofs]);
            gload_lds16(gb + k0 + 32 + 16 * K, &Bl[nxt][lofs + 512]);
        }
        bf16x8 af[4], bfr[4];
        #pragma unroll
        for (int m = 0; m < 4; m++)
            af[m] = *(const bf16x8*)(&Al[cur][(wm + m * 16 + l15) * 32 + rc]);
        #pragma unroll
        for (int n = 0; n < 4; n++)
            bfr[n] = *(const bf16x8*)(&Bl[cur][(wn + n * 16 + l15) * 32 + rc]);
        __builtin_amdgcn_s_setprio(1);
        #pragma unroll
        for (int m = 0; m < 4; m++)
            #pragma unroll
            for (int n = 0; n < 4; n++)
                acc[m][n] = __builtin_amdgcn_mfma_f32_16x16x32_bf16(af[m], bfr[n], acc[m][n], 0, 0, 0);
        __builtin_amdgcn_s_setprio(0);
        __syncthreads();
        cur = nxt;
    }

    #pragma unroll
    for (int n = 0; n < 4; n++) {
        int col = n0 + wn + n * 16 + l15;
        float bv = bias[col];
        #pragma unroll
        for (int m = 0; m < 4; m++)
            #pragma unroll
            for (int j = 0; j < 4; j++) {
                int row = m0 + wm + m * 16 + lhi * 4 + j;
                out[row * N + col] = acc[m][n][j] + bv;
            }
    }
}

extern "C" void kernel_launch(void* const* d_in, const int* in_sizes, int n_in,
                              void* d_out, int out_size, void* d_ws, size_t ws_size,
                              hipStream_t stream)
{
    const float* x      = (const float*)d_in[0];
    const float* w_qkv  = (const float*)d_in[1];
    const float* b_qkv  = (const float*)d_in[2];
    const float* w_proj = (const float*)d_in[3];
    const float* b_proj = (const float*)d_in[4];
    float* out = (float*)d_out;

    const size_t SEG = (size_t)8 * 1024 * 1024;
    unsigned short* q_ws    = (unsigned short*)d_ws;
    unsigned short* k_ws    = q_ws + SEG;
    unsigned short* vT_ws   = k_ws + SEG;
    unsigned short* attn_ws = vT_ws + SEG;

    unsigned short* x_bf   = (unsigned short*)d_out;          // d_out as scratch
    unsigned short* wqkvT  = x_bf + SEG;
    unsigned short* wprojT = q_ws;                            // dead after attn

    cvt_bf16<<<4096, 256, 0, stream>>>(x, x_bf);
    transpose_w<<<dim3(16, 48), 256, 0, stream>>>(w_qkv, wqkvT, 1024, 3072);
    qkv_gemm2<<<dim3(64, 24), 256, 0, stream>>>(x_bf, wqkvT, b_qkv, q_ws, k_ws, vT_ws);
    attn_fwd<<<dim3(64, 16), 256, 0, stream>>>(q_ws, k_ws, vT_ws, attn_ws);
    transpose_w<<<dim3(16, 16), 256, 0, stream>>>(w_proj, wprojT, 1024, 1024);
    proj_gemm2<<<dim3(64, 8), 256, 0, stream>>>(attn_ws, wprojT, b_proj, out);
}